// Round 5
// baseline (700.342 us; speedup 1.0000x reference)
//
#include <hip/hip_runtime.h>
#include <hip/hip_bf16.h>

// Problem constants
#define Bb 8
#define Ss 1024
#define Dd 1024
#define Hh 16
#define DHh 64
#define FFf 4096

typedef __hip_bfloat16 bf16;
typedef __attribute__((ext_vector_type(8))) __bf16 bf16x8;
typedef __attribute__((ext_vector_type(4))) float f32x4;

__device__ __forceinline__ unsigned short f2bu(float f) {
  __hip_bfloat16 h = __float2bfloat16(f);
  return __builtin_bit_cast(unsigned short, h);
}

#define MFMA16(a, b, c) __builtin_amdgcn_mfma_f32_16x16x32_bf16((a), (b), (c), 0, 0, 0)

__device__ __forceinline__ void gl_lds16(const void* g, void* l) {
  __builtin_amdgcn_global_load_lds(
      (const __attribute__((address_space(1))) unsigned int*)g,
      (__attribute__((address_space(3))) unsigned int*)l, 16, 0, 0);
}

// ---------------------------------------------------------------------------
// f32 -> bf16 elementwise convert
// ---------------------------------------------------------------------------
__global__ __launch_bounds__(256) void f32_to_bf16_vec(const float* __restrict__ in,
                                                       bf16* __restrict__ out, int n4) {
  int i = blockIdx.x * 256 + threadIdx.x;
  if (i < n4) {
    float4 v = ((const float4*)in)[i];
    union { unsigned short u[4]; uint2 q; } r;
    r.u[0] = f2bu(v.x); r.u[1] = f2bu(v.y); r.u[2] = f2bu(v.z); r.u[3] = f2bu(v.w);
    ((uint2*)out)[i] = r.q;
  }
}

// ---------------------------------------------------------------------------
// Batched 32x32 LDS-tiled transpose: src f32 [R][C] -> dst bf16 [C][R]
// ---------------------------------------------------------------------------
__global__ __launch_bounds__(256) void transpose_f32_bf16(const float* __restrict__ src,
                                                          bf16* __restrict__ dst,
                                                          int R, int C,
                                                          long sbatch, long dbatch) {
  __shared__ float tile[32][33];
  src += (size_t)blockIdx.z * sbatch;
  dst += (size_t)blockIdx.z * dbatch;
  int c0 = blockIdx.x * 32, r0 = blockIdx.y * 32;
  int tx = threadIdx.x & 31;
  int ty = threadIdx.x >> 5;  // 0..7
#pragma unroll
  for (int kk = 0; kk < 4; ++kk)
    tile[ty + kk * 8][tx] = src[(size_t)(r0 + ty + kk * 8) * C + c0 + tx];
  __syncthreads();
#pragma unroll
  for (int kk = 0; kk < 4; ++kk)
    dst[(size_t)(c0 + ty + kk * 8) * R + r0 + tx] = __float2bfloat16(tile[tx][ty + kk * 8]);
}

// ---------------------------------------------------------------------------
// 256x256 8-phase GEMM: C[M,N] = A[M,K] * Bt[N,K]^T (+bias epilogues)
// BK=64, 512 thr = 8 waves (2M x 4N), per-wave 128x64 out = 8x4 mfma frags.
// LDS 128KB: 2 dbuf x (A 32KB + B 32KB). Swizzle: byte ^= (row&1)<<6 (both
// sides: inverse-permuted global source for gl_lds, XOR'd ds_read addr) ->
// frag reads 8-deep conflict-free. Phases: q=0..3 per K-tile; phase 0 reads
// all 8 B-frags + A quad0 (12 ds_read_b128), phases 1-3 read A quads.
// Staging (proven race-free under phase barriers): B of buf[cur] dead after
// phase 0, A quad q of buf[cur] dead after phase q =>
//   p0,p1: stage A units of tile t+1 -> buf[nxt]
//   p2,p3: stage B units of tile t+2 -> buf[cur] (B region, dead)
// Boundary: vmcnt(4) (t+2's 4 B loads in flight; never 0 except tail).
// ---------------------------------------------------------------------------
enum { EPI_QKV = 0, EPI_WO = 1, EPI_FFN1 = 2, EPI_FFN2 = 3 };

__device__ __forceinline__ void stage_tile(const bf16* __restrict__ G, int ldK,
                                           int row0, int t, int u,
                                           unsigned char* ldsbase, int tid) {
  const int r = u * 64 + (tid >> 3);                        // row in 256-tile
  const int seg = (tid & 7) ^ (((tid >> 3) & 1) << 2);      // inverse-swizzled src seg
  gl_lds16(G + (size_t)(row0 + r) * ldK + t * 64 + seg * 8,
           ldsbase + u * 8192 + (tid >> 6) * 1024);
}

template <int EPI>
__global__ __launch_bounds__(512, 2) void gemm256(const bf16* __restrict__ A,
                                                  const bf16* __restrict__ Bt,
                                                  int M, int N, int K,
                                                  const float* __restrict__ bias0,
                                                  const float* __restrict__ bias1,
                                                  const float* __restrict__ bias2,
                                                  void* __restrict__ o0,
                                                  void* __restrict__ o1,
                                                  void* __restrict__ o2) {
  extern __shared__ __align__(16) unsigned char sm[];
  const int tid = threadIdx.x;
  const int lane = tid & 63;
  const int w = tid >> 6;
  const int wr = w >> 2, wc = w & 3;
  const int rl = lane & 15, ks4 = lane >> 4;
  const int NTm = M >> 8, NTn = N >> 8;
  const int nwg = NTm * NTn;
  // bijective XCD swizzle (nwg % 8 == 0 for all our shapes), col-major grouping
  const int swz = (blockIdx.x & 7) * (nwg >> 3) + (blockIdx.x >> 3);
  const int mt = swz % NTm, nt = swz / NTm;
  const int m0 = mt << 8, n0 = nt << 8;
  const int NT = K >> 6;

  f32x4 acc[8][4];
  const f32x4 z4 = {0.f, 0.f, 0.f, 0.f};
#pragma unroll
  for (int i = 0; i < 8; ++i)
#pragma unroll
    for (int j = 0; j < 4; ++j) acc[i][j] = z4;

  // ---- prologue: T0 A+B (8 units), T1 B (4 units); wait all but last 4 ----
#pragma unroll
  for (int u = 0; u < 4; ++u) stage_tile(A, K, m0, 0, u, sm, tid);
#pragma unroll
  for (int u = 0; u < 4; ++u) stage_tile(Bt, K, n0, 0, u, sm + 32768, tid);
  if (NT > 1) {
#pragma unroll
    for (int u = 0; u < 4; ++u) stage_tile(Bt, K, n0, 1, u, sm + 65536 + 32768, tid);
    asm volatile("s_waitcnt vmcnt(4)" ::: "memory");
  } else {
    asm volatile("s_waitcnt vmcnt(0)" ::: "memory");
  }
  __builtin_amdgcn_s_barrier();

  for (int t = 0; t < NT; ++t) {
    unsigned char* Al = sm + ((t & 1) << 16);
    unsigned char* Bl = Al + 32768;
    unsigned char* AlN = sm + (((t + 1) & 1) << 16);
    bf16x8 bfr[4][2], afr[2][2];

    // ---------------- phase 0: 8 B-frags + A quad0; stage A.u0/u2(t+1) ----
#pragma unroll
    for (int fc = 0; fc < 4; ++fc)
#pragma unroll
      for (int kk = 0; kk < 2; ++kk) {
        const int rr = wc * 64 + fc * 16 + rl;
        bfr[fc][kk] = *(const bf16x8*)(Bl + rr * 128 + ((kk ^ (rr & 1)) << 6) + ks4 * 16);
      }
#pragma unroll
    for (int i = 0; i < 2; ++i)
#pragma unroll
      for (int kk = 0; kk < 2; ++kk) {
        const int r = wr * 128 + i * 16 + rl;
        afr[i][kk] = *(const bf16x8*)(Al + r * 128 + ((kk ^ (r & 1)) << 6) + ks4 * 16);
      }
    if (t + 1 < NT) {
      stage_tile(A, K, m0, t + 1, 0, AlN, tid);
      stage_tile(A, K, m0, t + 1, 2, AlN, tid);
    }
    __builtin_amdgcn_s_barrier();
    __builtin_amdgcn_s_setprio(1);
#pragma unroll
    for (int i = 0; i < 2; ++i)
#pragma unroll
      for (int fc = 0; fc < 4; ++fc)
#pragma unroll
        for (int kk = 0; kk < 2; ++kk)
          acc[i][fc] = MFMA16(afr[i][kk], bfr[fc][kk], acc[i][fc]);
    __builtin_amdgcn_s_setprio(0);
    __builtin_amdgcn_s_barrier();

    // ---------------- phases 1..3 ----------------------------------------
#pragma unroll
    for (int q = 1; q < 4; ++q) {
#pragma unroll
      for (int i = 0; i < 2; ++i)
#pragma unroll
        for (int kk = 0; kk < 2; ++kk) {
          const int r = wr * 128 + (q * 2 + i) * 16 + rl;
          afr[i][kk] = *(const bf16x8*)(Al + r * 128 + ((kk ^ (r & 1)) << 6) + ks4 * 16);
        }
      if (q == 1) {
        if (t + 1 < NT) {
          stage_tile(A, K, m0, t + 1, 1, AlN, tid);
          stage_tile(A, K, m0, t + 1, 3, AlN, tid);
        }
      } else if (q == 2) {
        if (t + 2 < NT) {
          stage_tile(Bt, K, n0, t + 2, 0, Bl, tid);
          stage_tile(Bt, K, n0, t + 2, 1, Bl, tid);
        }
      } else {
        if (t + 2 < NT) {
          stage_tile(Bt, K, n0, t + 2, 2, Bl, tid);
          stage_tile(Bt, K, n0, t + 2, 3, Bl, tid);
        }
      }
      __builtin_amdgcn_s_barrier();
      __builtin_amdgcn_s_setprio(1);
#pragma unroll
      for (int i = 0; i < 2; ++i)
#pragma unroll
        for (int fc = 0; fc < 4; ++fc)
#pragma unroll
          for (int kk = 0; kk < 2; ++kk)
            acc[q * 2 + i][fc] = MFMA16(afr[i][kk], bfr[fc][kk], acc[q * 2 + i][fc]);
      __builtin_amdgcn_s_setprio(0);
      if (q == 3) {
        // tile boundary: ensure tile t+1 (A issued p0/p1, B issued at t-1)
        // fully landed; leave t+2's 4 B loads in flight.
        if (t + 2 < NT) {
          asm volatile("s_waitcnt vmcnt(4)" ::: "memory");
        } else if (t + 1 < NT) {
          asm volatile("s_waitcnt vmcnt(0)" ::: "memory");
        }
      }
      __builtin_amdgcn_s_barrier();
    }
  }

  // ---- epilogue. C/D frag layout: row = ks4*4 + p, col = rl ----
  const int rbase = ks4 * 4;
  if constexpr (EPI == EPI_QKV) {
    const int which = n0 >> 10;  // 0=q,1=k,2=v (256-tile never straddles 1024)
    const float* bias = which == 0 ? bias0 : (which == 1 ? bias1 : bias2);
    bf16* dst = (bf16*)(which == 0 ? o0 : (which == 1 ? o1 : o2));
#pragma unroll
    for (int fr = 0; fr < 8; ++fr) {
#pragma unroll
      for (int fc = 0; fc < 4; ++fc) {
        const int gcol = n0 + wc * 64 + fc * 16 + rl;
        const int cc = gcol & 1023;
        const int hh = cc >> 6, e = cc & 63;
        const float bval = bias[cc];
#pragma unroll
        for (int p = 0; p < 4; ++p) {
          const int grow = m0 + wr * 128 + fr * 16 + rbase + p;
          const int bidx = grow >> 10, s = grow & 1023;
          if (which == 2) {
            // V stored transposed per head: [B,H,DH,S]
            dst[(((size_t)bidx * Hh + hh) * DHh + e) * Ss + s] =
                __float2bfloat16(acc[fr][fc][p] + bval);
          } else {
            dst[(((size_t)bidx * Hh + hh) * Ss + s) * DHh + e] =
                __float2bfloat16(acc[fr][fc][p] + bval);
          }
        }
      }
    }
  } else if constexpr (EPI == EPI_WO || EPI == EPI_FFN2) {
    float* dst = (float*)o0;
#pragma unroll
    for (int fr = 0; fr < 8; ++fr) {
#pragma unroll
      for (int fc = 0; fc < 4; ++fc) {
        const int gcol = n0 + wc * 64 + fc * 16 + rl;
        const float bval = bias0[gcol];
#pragma unroll
        for (int p = 0; p < 4; ++p) {
          const int grow = m0 + wr * 128 + fr * 16 + rbase + p;
          dst[(size_t)grow * N + gcol] = acc[fr][fc][p] + bval;
        }
      }
    }
  } else {  // EPI_FFN1: ReLU -> bf16
    bf16* dst = (bf16*)o0;
#pragma unroll
    for (int fr = 0; fr < 8; ++fr) {
#pragma unroll
      for (int fc = 0; fc < 4; ++fc) {
        const int gcol = n0 + wc * 64 + fc * 16 + rl;
        const float bval = bias0[gcol];
#pragma unroll
        for (int p = 0; p < 4; ++p) {
          const int grow = m0 + wr * 128 + fr * 16 + rbase + p;
          dst[(size_t)grow * N + gcol] =
              __float2bfloat16(fmaxf(acc[fr][fc][p] + bval, 0.f));
        }
      }
    }
  }
}

// ---------------------------------------------------------------------------
// Flash attention v2 (unchanged from verified round-4 kernel)
// ---------------------------------------------------------------------------
__global__ __launch_bounds__(256) void attn_kernel(const bf16* __restrict__ q,
                                                   const bf16* __restrict__ k,
                                                   const bf16* __restrict__ v,
                                                   bf16* __restrict__ ctx) {
  __shared__ __align__(16) unsigned short Kl[64 * 64];
  __shared__ __align__(16) unsigned short Vt[64 * 64];
  __shared__ __align__(16) unsigned short Pl[4 * 16 * 72];

  const int bid = blockIdx.x;
  const int xcd = bid & 7;
  const int s8 = bid >> 3;             // 0..255
  const int hg = xcd + 8 * (s8 >> 4);  // 0..127  (b*16+h)
  const int qi = s8 & 15;
  const int b = hg >> 4, h = hg & 15;
  const int q0 = qi * 64;
  const size_t head = (size_t)hg << 16;  // hg * S * DH
  const bf16* Qp = q + head;
  const bf16* Kp = k + head;
  const bf16* Vp = v + head;  // per-head [DH][S]

  const int t = threadIdx.x;
  const int w = t >> 6;
  const int lane = t & 63;
  const int rl = lane & 15;
  const int ks = lane >> 4;  // 0..3
  const int rx = rl & 7;

  const int qrow = q0 + w * 16 + rl;
  const bf16x8 aq0 = *(const bf16x8*)(Qp + (size_t)qrow * 64 + ks * 8);
  const bf16x8 aq1 = *(const bf16x8*)(Qp + (size_t)qrow * 64 + 32 + ks * 8);

  f32x4 o[4];
  const f32x4 z4 = {0.f, 0.f, 0.f, 0.f};
#pragma unroll
  for (int c = 0; c < 4; ++c) o[c] = z4;
  float m4[4] = {-1e30f, -1e30f, -1e30f, -1e30f};
  float l4[4] = {0.f, 0.f, 0.f, 0.f};

  const int srow8 = lane >> 3;  // 0..7
  const int sseg = lane & 7;    // 0..7
  unsigned short* Pw = Pl + w * 16 * 72;
  const float scale = 0.125f;  // 1/sqrt(64)

  for (int kv0 = 0; kv0 < Ss; kv0 += 64) {
    __syncthreads();
#pragma unroll
    for (int r = 0; r < 2; ++r) {
      const int rb = w * 16 + r * 8;
      const int row = rb + srow8;
      gl_lds16(Kp + (size_t)(kv0 + row) * 64 + (sseg ^ (row & 7)) * 8,
               Kl + rb * 64);
      gl_lds16(Vp + (size_t)row * Ss + kv0 + (sseg ^ (row & 7)) * 8,
               Vt + rb * 64);
    }
    __syncthreads();

    f32x4 s4[4];
#pragma unroll
    for (int f = 0; f < 4; ++f) s4[f] = z4;
#pragma unroll
    for (int f = 0; f < 4; ++f) {
      const int row = f * 16 + rl;
      const bf16x8 b0 = *(const bf16x8*)(Kl + row * 64 + (ks ^ rx) * 8);
      const bf16x8 b1 = *(const bf16x8*)(Kl + row * 64 + ((4 + ks) ^ rx) * 8);
      s4[f] = MFMA16(aq0, b0, s4[f]);
      s4[f] = MFMA16(aq1, b1, s4[f]);
    }

    float mx[4], sm[4];
#pragma unroll
    for (int j = 0; j < 4; ++j) {
      s4[0][j] *= scale; s4[1][j] *= scale; s4[2][j] *= scale; s4[3][j] *= scale;
      mx[j] = fmaxf(fmaxf(s4[0][j], s4[1][j]), fmaxf(s4[2][j], s4[3][j]));
    }
#pragma unroll
    for (int mm = 1; mm < 16; mm <<= 1)
#pragma unroll
      for (int j = 0; j < 4; ++j) mx[j] = fmaxf(mx[j], __shfl_xor(mx[j], mm, 64));
#pragma unroll
    for (int j = 0; j < 4; ++j) {
      const float mn = fmaxf(m4[j], mx[j]);
      const float corr = __expf(m4[j] - mn);
      m4[j] = mn;
#pragma unroll
      for (int f = 0; f < 4; ++f) s4[f][j] = __expf(s4[f][j] - mn);
      sm[j] = (s4[0][j] + s4[1][j]) + (s4[2][j] + s4[3][j]);
      l4[j] *= corr;
#pragma unroll
      for (int c = 0; c < 4; ++c) o[c][j] *= corr;
    }
#pragma unroll
    for (int mm = 1; mm < 16; mm <<= 1)
#pragma unroll
      for (int j = 0; j < 4; ++j) sm[j] += __shfl_xor(sm[j], mm, 64);
#pragma unroll
    for (int j = 0; j < 4; ++j) l4[j] += sm[j];

#pragma unroll
    for (int f = 0; f < 4; ++f)
#pragma unroll
      for (int j = 0; j < 4; ++j)
        Pw[(ks * 4 + j) * 72 + f * 16 + rl] = f2bu(s4[f][j]);
    asm volatile("s_waitcnt lgkmcnt(0)" ::: "memory");
    __builtin_amdgcn_sched_barrier(0);
    const bf16x8 pa0 = *(const bf16x8*)(Pw + rl * 72 + ks * 8);
    const bf16x8 pa1 = *(const bf16x8*)(Pw + rl * 72 + 32 + ks * 8);

#pragma unroll
    for (int c = 0; c < 4; ++c) {
      const int row = c * 16 + rl;
      const bf16x8 v0 = *(const bf16x8*)(Vt + row * 64 + (ks ^ rx) * 8);
      const bf16x8 v1 = *(const bf16x8*)(Vt + row * 64 + ((4 + ks) ^ rx) * 8);
      o[c] = MFMA16(pa0, v0, o[c]);
      o[c] = MFMA16(pa1, v1, o[c]);
    }
  }

  float inv[4];
#pragma unroll
  for (int j = 0; j < 4; ++j) inv[j] = 1.0f / l4[j];
#pragma unroll
  for (int c = 0; c < 4; ++c) {
#pragma unroll
    for (int j = 0; j < 4; ++j) {
      const int sq = q0 + w * 16 + ks * 4 + j;
      const int dh = c * 16 + rl;
      ctx[(((size_t)b * Ss + sq) * Hh + h) * DHh + dh] =
          __float2bfloat16(o[c][j] * inv[j]);
    }
  }
}

// ---------------------------------------------------------------------------
// Fused residual + LayerNorm
// ---------------------------------------------------------------------------
__global__ __launch_bounds__(256) void ln_fused(const float* __restrict__ a,
                                                const float* __restrict__ bsrc,
                                                const float* __restrict__ g,
                                                const float* __restrict__ be,
                                                float* __restrict__ of,
                                                bf16* __restrict__ ob) {
  const int row = blockIdx.x, t = threadIdx.x;
  const float4 va = ((const float4*)(a + (size_t)row * Dd))[t];
  const float4 vb = ((const float4*)(bsrc + (size_t)row * Dd))[t];
  const float x0 = va.x + vb.x, x1 = va.y + vb.y, x2 = va.z + vb.z, x3 = va.w + vb.w;
  float s = x0 + x1 + x2 + x3;
  float qq = x0 * x0 + x1 * x1 + x2 * x2 + x3 * x3;
#pragma unroll
  for (int m = 1; m < 64; m <<= 1) {
    s += __shfl_xor(s, m, 64);
    qq += __shfl_xor(qq, m, 64);
  }
  __shared__ float ss[4], sq2[4];
  if ((t & 63) == 0) {
    ss[t >> 6] = s;
    sq2[t >> 6] = qq;
  }
  __syncthreads();
  s = ss[0] + ss[1] + ss[2] + ss[3];
  qq = sq2[0] + sq2[1] + sq2[2] + sq2[3];
  const float mu = s * (1.0f / Dd);
  const float var = qq * (1.0f / Dd) - mu * mu;
  const float rs = rsqrtf(var + 1e-5f);
  const float4 gv = ((const float4*)g)[t];
  const float4 bv = ((const float4*)be)[t];
  const float y0 = (x0 - mu) * rs * gv.x + bv.x;
  const float y1 = (x1 - mu) * rs * gv.y + bv.y;
  const float y2 = (x2 - mu) * rs * gv.z + bv.z;
  const float y3 = (x3 - mu) * rs * gv.w + bv.w;
  if (of) ((float4*)(of + (size_t)row * Dd))[t] = make_float4(y0, y1, y2, y3);
  if (ob) {
    union { unsigned short u[4]; uint2 qv; } r;
    r.u[0] = f2bu(y0); r.u[1] = f2bu(y1); r.u[2] = f2bu(y2); r.u[3] = f2bu(y3);
    ((uint2*)(ob + (size_t)row * Dd))[t] = r.qv;
  }
}

// ---------------------------------------------------------------------------
extern "C" void kernel_launch(void* const* d_in, const int* in_sizes, int n_in,
                              void* d_out, int out_size, void* d_ws, size_t ws_size,
                              hipStream_t stream) {
  const float* x   = (const float*)d_in[0];
  const float* wq  = (const float*)d_in[1];
  const float* bq  = (const float*)d_in[2];
  const float* wk  = (const float*)d_in[3];
  const float* bk  = (const float*)d_in[4];
  const float* wv  = (const float*)d_in[5];
  const float* bv  = (const float*)d_in[6];
  const float* wo  = (const float*)d_in[7];
  const float* bo  = (const float*)d_in[8];
  const float* w1  = (const float*)d_in[9];
  const float* b1  = (const float*)d_in[10];
  const float* w2  = (const float*)d_in[11];
  const float* b2  = (const float*)d_in[12];
  const float* g1  = (const float*)d_in[13];
  const float* be1 = (const float*)d_in[14];
  const float* g2  = (const float*)d_in[15];
  const float* be2 = (const float*)d_in[16];
  float* out = (float*)d_out;

  char* ws = (char*)d_ws;
  const size_t MB = 1u << 20;
  bf16* qb    = (bf16*)(ws + 0);         // 16 MiB  [B,H,S,DH]
  bf16* kb    = (bf16*)(ws + 16 * MB);   // 16 MiB  [B,H,S,DH]
  bf16* vvb   = (bf16*)(ws + 32 * MB);   // 16 MiB  [B,H,DH,S]  (transposed!)
  bf16* xb    = (bf16*)(ws + 48 * MB);   // 16 MiB  [B*S, D]
  bf16* hb    = (bf16*)(ws + 0);         // 64 MiB, reuses q/k/v/xb after attn
  bf16* ctx   = (bf16*)(ws + 64 * MB);   // 16 MiB  [B*S, H*DH]
  float* y    = (float*)(ws + 80 * MB);  // 32 MiB  f32 (attn-out, then ffn-out)
  float* x1f  = (float*)(ws + 112 * MB); // 32 MiB  f32 post-LN1
  bf16* x1b   = (bf16*)(ws + 144 * MB);  // 16 MiB  bf16 post-LN1
  bf16* btqkv = (bf16*)(ws + 160 * MB);  // 6 MiB   [3072][1024]
  bf16* wot   = (bf16*)(ws + 166 * MB);  // 2 MiB   [1024][1024]
  bf16* w1t   = (bf16*)(ws + 168 * MB);  // 8 MiB   [4096][1024]
  bf16* w2t   = (bf16*)(ws + 176 * MB);  // 8 MiB   [1024][4096]

  // --- weight/activation conversion ---
  f32_to_bf16_vec<<<8192, 256, 0, stream>>>(x, xb, Bb * Ss * Dd / 4);
  transpose_f32_bf16<<<dim3(2, 32, 16), 256, 0, stream>>>(wq, btqkv + 0 * 1048576,
                                                          Dd, DHh, 65536, 65536);
  transpose_f32_bf16<<<dim3(2, 32, 16), 256, 0, stream>>>(wk, btqkv + 1 * 1048576,
                                                          Dd, DHh, 65536, 65536);
  transpose_f32_bf16<<<dim3(2, 32, 16), 256, 0, stream>>>(wv, btqkv + 2 * 1048576,
                                                          Dd, DHh, 65536, 65536);
  transpose_f32_bf16<<<dim3(32, 32, 1), 256, 0, stream>>>(wo, wot, Hh * DHh, Dd, 0, 0);
  transpose_f32_bf16<<<dim3(128, 32, 1), 256, 0, stream>>>(w1, w1t, Dd, FFf, 0, 0);
  transpose_f32_bf16<<<dim3(32, 128, 1), 256, 0, stream>>>(w2, w2t, FFf, Dd, 0, 0);

  // --- QKV projection (V written transposed per head) ---
  gemm256<EPI_QKV><<<384, 512, 131072, stream>>>(
      xb, btqkv, Bb * Ss, 3 * Hh * DHh, Dd, bq, bk, bv, qb, kb, vvb);

  // --- attention ---
  attn_kernel<<<2048, 256, 0, stream>>>(qb, kb, vvb, ctx);

  // --- output projection ---
  gemm256<EPI_WO><<<128, 512, 131072, stream>>>(
      ctx, wot, Bb * Ss, Dd, Hh * DHh, bo, nullptr, nullptr, y, nullptr, nullptr);

  // --- residual + LN1 ---
  ln_fused<<<Bb * Ss, 256, 0, stream>>>(x, y, g1, be1, x1f, x1b);

  // --- FFN ---
  gemm256<EPI_FFN1><<<512, 512, 131072, stream>>>(
      x1b, w1t, Bb * Ss, FFf, Dd, b1, nullptr, nullptr, hb, nullptr, nullptr);
  gemm256<EPI_FFN2><<<128, 512, 131072, stream>>>(
      hb, w2t, Bb * Ss, Dd, FFf, b2, nullptr, nullptr, y, nullptr, nullptr);

  // --- residual + LN2 -> out ---
  ln_fused<<<Bb * Ss, 256, 0, stream>>>(x1f, y, g2, be2, out, nullptr);
}

// Round 6
// 625.321 us; speedup vs baseline: 1.1200x; 1.1200x over previous
//
#include <hip/hip_runtime.h>
#include <hip/hip_bf16.h>

// Problem constants
#define Bb 8
#define Ss 1024
#define Dd 1024
#define Hh 16
#define DHh 64
#define FFf 4096

typedef __hip_bfloat16 bf16;
typedef __attribute__((ext_vector_type(8))) __bf16 bf16x8;
typedef __attribute__((ext_vector_type(4))) float f32x4;

__device__ __forceinline__ unsigned short f2bu(float f) {
  __hip_bfloat16 h = __float2bfloat16(f);
  return __builtin_bit_cast(unsigned short, h);
}

#define MFMA16(a, b, c) __builtin_amdgcn_mfma_f32_16x16x32_bf16((a), (b), (c), 0, 0, 0)

__device__ __forceinline__ void gl_lds16(const void* g, void* l) {
  __builtin_amdgcn_global_load_lds(
      (const __attribute__((address_space(1))) unsigned int*)g,
      (__attribute__((address_space(3))) unsigned int*)l, 16, 0, 0);
}

// ---------------------------------------------------------------------------
// f32 -> bf16 elementwise convert
// ---------------------------------------------------------------------------
__global__ __launch_bounds__(256) void f32_to_bf16_vec(const float* __restrict__ in,
                                                       bf16* __restrict__ out, int n4) {
  int i = blockIdx.x * 256 + threadIdx.x;
  if (i < n4) {
    float4 v = ((const float4*)in)[i];
    union { unsigned short u[4]; uint2 q; } r;
    r.u[0] = f2bu(v.x); r.u[1] = f2bu(v.y); r.u[2] = f2bu(v.z); r.u[3] = f2bu(v.w);
    ((uint2*)out)[i] = r.q;
  }
}

// ---------------------------------------------------------------------------
// Batched 32x32 LDS-tiled transpose: src f32 [R][C] -> dst bf16 [C][R]
// ---------------------------------------------------------------------------
__global__ __launch_bounds__(256) void transpose_f32_bf16(const float* __restrict__ src,
                                                          bf16* __restrict__ dst,
                                                          int R, int C,
                                                          long sbatch, long dbatch) {
  __shared__ float tile[32][33];
  src += (size_t)blockIdx.z * sbatch;
  dst += (size_t)blockIdx.z * dbatch;
  int c0 = blockIdx.x * 32, r0 = blockIdx.y * 32;
  int tx = threadIdx.x & 31;
  int ty = threadIdx.x >> 5;  // 0..7
#pragma unroll
  for (int kk = 0; kk < 4; ++kk)
    tile[ty + kk * 8][tx] = src[(size_t)(r0 + ty + kk * 8) * C + c0 + tx];
  __syncthreads();
#pragma unroll
  for (int kk = 0; kk < 4; ++kk)
    dst[(size_t)(c0 + ty + kk * 8) * R + r0 + tx] = __float2bfloat16(tile[tx][ty + kk * 8]);
}

// ---------------------------------------------------------------------------
// 256x256 8-phase GEMM: C[M,N] = A[M,K] * Bt[N,K]^T (+bias epilogues)
// BK=64, 512 thr = 8 waves (2M x 4N), per-wave 128x64 out = 8x4 mfma frags.
// LDS 128KB: 2 dbuf x (A 32KB + B 32KB).
// Swizzle (FIXED r6): 3-bit seg swizzle, seg' = seg ^ (row&7) over the 8
// 16B-segments of a 128B row (both sides: inverse-permuted global source for
// gl_lds, XOR'd ds_read addr). Each of 8 seg values is read by exactly 8
// lanes -> 8 words/bank = wave64-b128 floor, conflict-free. (The r5 1-bit
// swizzle left an 8-way conflict: SQ_LDS_BANK_CONFLICT 1.9e7.)
// Staging (race-free under phase barriers): B of buf[cur] dead after phase 0,
// A quad q dead after phase q =>
//   p0,p1: stage A units of tile t+1 -> buf[nxt]
//   p2,p3: stage B units of tile t+2 -> buf[cur] (B region, dead)
// Boundary: vmcnt(4) (t+2's 4 B loads in flight; never 0 except tail).
// ---------------------------------------------------------------------------
enum { EPI_QKV = 0, EPI_WO = 1, EPI_FFN1 = 2, EPI_FFN2 = 3 };

__device__ __forceinline__ void stage_tile(const bf16* __restrict__ G, int ldK,
                                           int row0, int t, int u,
                                           unsigned char* ldsbase, int tid) {
  const int r = u * 64 + (tid >> 3);                    // row in 256-tile
  const int seg = (tid & 7) ^ ((tid >> 3) & 7);         // inverse-swizzled src seg
  gl_lds16(G + (size_t)(row0 + r) * ldK + t * 64 + seg * 8,
           ldsbase + u * 8192 + (tid >> 6) * 1024);
}

template <int EPI>
__global__ __launch_bounds__(512, 2) void gemm256(const bf16* __restrict__ A,
                                                  const bf16* __restrict__ Bt,
                                                  int M, int N, int K,
                                                  const float* __restrict__ bias0,
                                                  const float* __restrict__ bias1,
                                                  const float* __restrict__ bias2,
                                                  void* __restrict__ o0,
                                                  void* __restrict__ o1,
                                                  void* __restrict__ o2) {
  extern __shared__ __align__(16) unsigned char sm[];
  const int tid = threadIdx.x;
  const int lane = tid & 63;
  const int w = tid >> 6;
  const int wr = w >> 2, wc = w & 3;
  const int rl = lane & 15, ks4 = lane >> 4;
  const int NTm = M >> 8, NTn = N >> 8;
  const int nwg = NTm * NTn;
  // bijective XCD swizzle (nwg % 8 == 0 for all our shapes), col-major grouping
  const int swz = (blockIdx.x & 7) * (nwg >> 3) + (blockIdx.x >> 3);
  const int mt = swz % NTm, nt = swz / NTm;
  const int m0 = mt << 8, n0 = nt << 8;
  const int NT = K >> 6;

  f32x4 acc[8][4];
  const f32x4 z4 = {0.f, 0.f, 0.f, 0.f};
#pragma unroll
  for (int i = 0; i < 8; ++i)
#pragma unroll
    for (int j = 0; j < 4; ++j) acc[i][j] = z4;

  // ---- prologue: T0 A+B (8 units), T1 B (4 units); wait all but last 4 ----
#pragma unroll
  for (int u = 0; u < 4; ++u) stage_tile(A, K, m0, 0, u, sm, tid);
#pragma unroll
  for (int u = 0; u < 4; ++u) stage_tile(Bt, K, n0, 0, u, sm + 32768, tid);
  if (NT > 1) {
#pragma unroll
    for (int u = 0; u < 4; ++u) stage_tile(Bt, K, n0, 1, u, sm + 65536 + 32768, tid);
    asm volatile("s_waitcnt vmcnt(4)" ::: "memory");
  } else {
    asm volatile("s_waitcnt vmcnt(0)" ::: "memory");
  }
  __builtin_amdgcn_s_barrier();

  for (int t = 0; t < NT; ++t) {
    unsigned char* Al = sm + ((t & 1) << 16);
    unsigned char* Bl = Al + 32768;
    unsigned char* AlN = sm + (((t + 1) & 1) << 16);
    bf16x8 bfr[4][2], afr[2][2];

    // ---------------- phase 0: 8 B-frags + A quad0; stage A.u0/u2(t+1) ----
#pragma unroll
    for (int fc = 0; fc < 4; ++fc)
#pragma unroll
      for (int kk = 0; kk < 2; ++kk) {
        const int rr = wc * 64 + fc * 16 + rl;
        bfr[fc][kk] = *(const bf16x8*)(Bl + rr * 128 + (((kk * 4 + ks4) ^ (rr & 7)) << 4));
      }
#pragma unroll
    for (int i = 0; i < 2; ++i)
#pragma unroll
      for (int kk = 0; kk < 2; ++kk) {
        const int r = wr * 128 + i * 16 + rl;
        afr[i][kk] = *(const bf16x8*)(Al + r * 128 + (((kk * 4 + ks4) ^ (r & 7)) << 4));
      }
    if (t + 1 < NT) {
      stage_tile(A, K, m0, t + 1, 0, AlN, tid);
      stage_tile(A, K, m0, t + 1, 2, AlN, tid);
    }
    __builtin_amdgcn_s_barrier();
    __builtin_amdgcn_s_setprio(1);
#pragma unroll
    for (int i = 0; i < 2; ++i)
#pragma unroll
      for (int fc = 0; fc < 4; ++fc)
#pragma unroll
        for (int kk = 0; kk < 2; ++kk)
          acc[i][fc] = MFMA16(afr[i][kk], bfr[fc][kk], acc[i][fc]);
    __builtin_amdgcn_s_setprio(0);
    __builtin_amdgcn_s_barrier();

    // ---------------- phases 1..3 ----------------------------------------
#pragma unroll
    for (int q = 1; q < 4; ++q) {
#pragma unroll
      for (int i = 0; i < 2; ++i)
#pragma unroll
        for (int kk = 0; kk < 2; ++kk) {
          const int r = wr * 128 + (q * 2 + i) * 16 + rl;
          afr[i][kk] = *(const bf16x8*)(Al + r * 128 + (((kk * 4 + ks4) ^ (r & 7)) << 4));
        }
      if (q == 1) {
        if (t + 1 < NT) {
          stage_tile(A, K, m0, t + 1, 1, AlN, tid);
          stage_tile(A, K, m0, t + 1, 3, AlN, tid);
        }
      } else if (q == 2) {
        if (t + 2 < NT) {
          stage_tile(Bt, K, n0, t + 2, 0, Bl, tid);
          stage_tile(Bt, K, n0, t + 2, 1, Bl, tid);
        }
      } else {
        if (t + 2 < NT) {
          stage_tile(Bt, K, n0, t + 2, 2, Bl, tid);
          stage_tile(Bt, K, n0, t + 2, 3, Bl, tid);
        }
      }
      __builtin_amdgcn_s_barrier();
      __builtin_amdgcn_s_setprio(1);
#pragma unroll
      for (int i = 0; i < 2; ++i)
#pragma unroll
        for (int fc = 0; fc < 4; ++fc)
#pragma unroll
          for (int kk = 0; kk < 2; ++kk)
            acc[q * 2 + i][fc] = MFMA16(afr[i][kk], bfr[fc][kk], acc[q * 2 + i][fc]);
      __builtin_amdgcn_s_setprio(0);
      if (q == 3) {
        // tile boundary: tile t+1 fully landed; t+2's 4 B loads stay in flight
        if (t + 2 < NT) {
          asm volatile("s_waitcnt vmcnt(4)" ::: "memory");
        } else if (t + 1 < NT) {
          asm volatile("s_waitcnt vmcnt(0)" ::: "memory");
        }
      }
      __builtin_amdgcn_s_barrier();
    }
  }

  // ---- epilogue. C/D frag layout: row = ks4*4 + p, col = rl ----
  const int rbase = ks4 * 4;
  if constexpr (EPI == EPI_QKV) {
    const int which = n0 >> 10;  // 0=q,1=k,2=v (256-tile never straddles 1024)
    const float* bias = which == 0 ? bias0 : (which == 1 ? bias1 : bias2);
    bf16* dst = (bf16*)(which == 0 ? o0 : (which == 1 ? o1 : o2));
#pragma unroll
    for (int fr = 0; fr < 8; ++fr) {
#pragma unroll
      for (int fc = 0; fc < 4; ++fc) {
        const int gcol = n0 + wc * 64 + fc * 16 + rl;
        const int cc = gcol & 1023;
        const int hh = cc >> 6, e = cc & 63;
        const float bval = bias[cc];
#pragma unroll
        for (int p = 0; p < 4; ++p) {
          const int grow = m0 + wr * 128 + fr * 16 + rbase + p;
          const int bidx = grow >> 10, s = grow & 1023;
          if (which == 2) {
            // V stored transposed per head: [B,H,DH,S]
            dst[(((size_t)bidx * Hh + hh) * DHh + e) * Ss + s] =
                __float2bfloat16(acc[fr][fc][p] + bval);
          } else {
            dst[(((size_t)bidx * Hh + hh) * Ss + s) * DHh + e] =
                __float2bfloat16(acc[fr][fc][p] + bval);
          }
        }
      }
    }
  } else if constexpr (EPI == EPI_WO || EPI == EPI_FFN2) {
    float* dst = (float*)o0;
#pragma unroll
    for (int fr = 0; fr < 8; ++fr) {
#pragma unroll
      for (int fc = 0; fc < 4; ++fc) {
        const int gcol = n0 + wc * 64 + fc * 16 + rl;
        const float bval = bias0[gcol];
#pragma unroll
        for (int p = 0; p < 4; ++p) {
          const int grow = m0 + wr * 128 + fr * 16 + rbase + p;
          dst[(size_t)grow * N + gcol] = acc[fr][fc][p] + bval;
        }
      }
    }
  } else {  // EPI_FFN1: ReLU -> bf16
    bf16* dst = (bf16*)o0;
#pragma unroll
    for (int fr = 0; fr < 8; ++fr) {
#pragma unroll
      for (int fc = 0; fc < 4; ++fc) {
        const int gcol = n0 + wc * 64 + fc * 16 + rl;
        const float bval = bias0[gcol];
#pragma unroll
        for (int p = 0; p < 4; ++p) {
          const int grow = m0 + wr * 128 + fr * 16 + rbase + p;
          dst[(size_t)grow * N + gcol] =
              __float2bfloat16(fmaxf(acc[fr][fc][p] + bval, 0.f));
        }
      }
    }
  }
}

// ---------------------------------------------------------------------------
// Flash attention v2 (unchanged, verified round-4)
// ---------------------------------------------------------------------------
__global__ __launch_bounds__(256) void attn_kernel(const bf16* __restrict__ q,
                                                   const bf16* __restrict__ k,
                                                   const bf16* __restrict__ v,
                                                   bf16* __restrict__ ctx) {
  __shared__ __align__(16) unsigned short Kl[64 * 64];
  __shared__ __align__(16) unsigned short Vt[64 * 64];
  __shared__ __align__(16) unsigned short Pl[4 * 16 * 72];

  const int bid = blockIdx.x;
  const int xcd = bid & 7;
  const int s8 = bid >> 3;             // 0..255
  const int hg = xcd + 8 * (s8 >> 4);  // 0..127  (b*16+h)
  const int qi = s8 & 15;
  const int b = hg >> 4, h = hg & 15;
  const int q0 = qi * 64;
  const size_t head = (size_t)hg << 16;  // hg * S * DH
  const bf16* Qp = q + head;
  const bf16* Kp = k + head;
  const bf16* Vp = v + head;  // per-head [DH][S]

  const int t = threadIdx.x;
  const int w = t >> 6;
  const int lane = t & 63;
  const int rl = lane & 15;
  const int ks = lane >> 4;  // 0..3
  const int rx = rl & 7;

  const int qrow = q0 + w * 16 + rl;
  const bf16x8 aq0 = *(const bf16x8*)(Qp + (size_t)qrow * 64 + ks * 8);
  const bf16x8 aq1 = *(const bf16x8*)(Qp + (size_t)qrow * 64 + 32 + ks * 8);

  f32x4 o[4];
  const f32x4 z4 = {0.f, 0.f, 0.f, 0.f};
#pragma unroll
  for (int c = 0; c < 4; ++c) o[c] = z4;
  float m4[4] = {-1e30f, -1e30f, -1e30f, -1e30f};
  float l4[4] = {0.f, 0.f, 0.f, 0.f};

  const int srow8 = lane >> 3;  // 0..7
  const int sseg = lane & 7;    // 0..7
  unsigned short* Pw = Pl + w * 16 * 72;
  const float scale = 0.125f;  // 1/sqrt(64)

  for (int kv0 = 0; kv0 < Ss; kv0 += 64) {
    __syncthreads();
#pragma unroll
    for (int r = 0; r < 2; ++r) {
      const int rb = w * 16 + r * 8;
      const int row = rb + srow8;
      gl_lds16(Kp + (size_t)(kv0 + row) * 64 + (sseg ^ (row & 7)) * 8,
               Kl + rb * 64);
      gl_lds16(Vp + (size_t)row * Ss + kv0 + (sseg ^ (row & 7)) * 8,
               Vt + rb * 64);
    }
    __syncthreads();

    f32x4 s4[4];
#pragma unroll
    for (int f = 0; f < 4; ++f) s4[f] = z4;
#pragma unroll
    for (int f = 0; f < 4; ++f) {
      const int row = f * 16 + rl;
      const bf16x8 b0 = *(const bf16x8*)(Kl + row * 64 + (ks ^ rx) * 8);
      const bf16x8 b1 = *(const bf16x8*)(Kl + row * 64 + ((4 + ks) ^ rx) * 8);
      s4[f] = MFMA16(aq0, b0, s4[f]);
      s4[f] = MFMA16(aq1, b1, s4[f]);
    }

    float mx[4], sm[4];
#pragma unroll
    for (int j = 0; j < 4; ++j) {
      s4[0][j] *= scale; s4[1][j] *= scale; s4[2][j] *= scale; s4[3][j] *= scale;
      mx[j] = fmaxf(fmaxf(s4[0][j], s4[1][j]), fmaxf(s4[2][j], s4[3][j]));
    }
#pragma unroll
    for (int mm = 1; mm < 16; mm <<= 1)
#pragma unroll
      for (int j = 0; j < 4; ++j) mx[j] = fmaxf(mx[j], __shfl_xor(mx[j], mm, 64));
#pragma unroll
    for (int j = 0; j < 4; ++j) {
      const float mn = fmaxf(m4[j], mx[j]);
      const float corr = __expf(m4[j] - mn);
      m4[j] = mn;
#pragma unroll
      for (int f = 0; f < 4; ++f) s4[f][j] = __expf(s4[f][j] - mn);
      sm[j] = (s4[0][j] + s4[1][j]) + (s4[2][j] + s4[3][j]);
      l4[j] *= corr;
#pragma unroll
      for (int c = 0; c < 4; ++c) o[c][j] *= corr;
    }
#pragma unroll
    for (int mm = 1; mm < 16; mm <<= 1)
#pragma unroll
      for (int j = 0; j < 4; ++j) sm[j] += __shfl_xor(sm[j], mm, 64);
#pragma unroll
    for (int j = 0; j < 4; ++j) l4[j] += sm[j];

#pragma unroll
    for (int f = 0; f < 4; ++f)
#pragma unroll
      for (int j = 0; j < 4; ++j)
        Pw[(ks * 4 + j) * 72 + f * 16 + rl] = f2bu(s4[f][j]);
    asm volatile("s_waitcnt lgkmcnt(0)" ::: "memory");
    __builtin_amdgcn_sched_barrier(0);
    const bf16x8 pa0 = *(const bf16x8*)(Pw + rl * 72 + ks * 8);
    const bf16x8 pa1 = *(const bf16x8*)(Pw + rl * 72 + 32 + ks * 8);

#pragma unroll
    for (int c = 0; c < 4; ++c) {
      const int row = c * 16 + rl;
      const bf16x8 v0 = *(const bf16x8*)(Vt + row * 64 + (ks ^ rx) * 8);
      const bf16x8 v1 = *(const bf16x8*)(Vt + row * 64 + ((4 + ks) ^ rx) * 8);
      o[c] = MFMA16(pa0, v0, o[c]);
      o[c] = MFMA16(pa1, v1, o[c]);
    }
  }

  float inv[4];
#pragma unroll
  for (int j = 0; j < 4; ++j) inv[j] = 1.0f / l4[j];
#pragma unroll
  for (int c = 0; c < 4; ++c) {
#pragma unroll
    for (int j = 0; j < 4; ++j) {
      const int sq = q0 + w * 16 + ks * 4 + j;
      const int dh = c * 16 + rl;
      ctx[(((size_t)b * Ss + sq) * Hh + h) * DHh + dh] =
          __float2bfloat16(o[c][j] * inv[j]);
    }
  }
}

// ---------------------------------------------------------------------------
// Fused residual + LayerNorm
// ---------------------------------------------------------------------------
__global__ __launch_bounds__(256) void ln_fused(const float* __restrict__ a,
                                                const float* __restrict__ bsrc,
                                                const float* __restrict__ g,
                                                const float* __restrict__ be,
                                                float* __restrict__ of,
                                                bf16* __restrict__ ob) {
  const int row = blockIdx.x, t = threadIdx.x;
  const float4 va = ((const float4*)(a + (size_t)row * Dd))[t];
  const float4 vb = ((const float4*)(bsrc + (size_t)row * Dd))[t];
  const float x0 = va.x + vb.x, x1 = va.y + vb.y, x2 = va.z + vb.z, x3 = va.w + vb.w;
  float s = x0 + x1 + x2 + x3;
  float qq = x0 * x0 + x1 * x1 + x2 * x2 + x3 * x3;
#pragma unroll
  for (int m = 1; m < 64; m <<= 1) {
    s += __shfl_xor(s, m, 64);
    qq += __shfl_xor(qq, m, 64);
  }
  __shared__ float ss[4], sq2[4];
  if ((t & 63) == 0) {
    ss[t >> 6] = s;
    sq2[t >> 6] = qq;
  }
  __syncthreads();
  s = ss[0] + ss[1] + ss[2] + ss[3];
  qq = sq2[0] + sq2[1] + sq2[2] + sq2[3];
  const float mu = s * (1.0f / Dd);
  const float var = qq * (1.0f / Dd) - mu * mu;
  const float rs = rsqrtf(var + 1e-5f);
  const float4 gv = ((const float4*)g)[t];
  const float4 bv = ((const float4*)be)[t];
  const float y0 = (x0 - mu) * rs * gv.x + bv.x;
  const float y1 = (x1 - mu) * rs * gv.y + bv.y;
  const float y2 = (x2 - mu) * rs * gv.z + bv.z;
  const float y3 = (x3 - mu) * rs * gv.w + bv.w;
  if (of) ((float4*)(of + (size_t)row * Dd))[t] = make_float4(y0, y1, y2, y3);
  if (ob) {
    union { unsigned short u[4]; uint2 qv; } r;
    r.u[0] = f2bu(y0); r.u[1] = f2bu(y1); r.u[2] = f2bu(y2); r.u[3] = f2bu(y3);
    ((uint2*)(ob + (size_t)row * Dd))[t] = r.qv;
  }
}

// ---------------------------------------------------------------------------
extern "C" void kernel_launch(void* const* d_in, const int* in_sizes, int n_in,
                              void* d_out, int out_size, void* d_ws, size_t ws_size,
                              hipStream_t stream) {
  const float* x   = (const float*)d_in[0];
  const float* wq  = (const float*)d_in[1];
  const float* bq  = (const float*)d_in[2];
  const float* wk  = (const float*)d_in[3];
  const float* bk  = (const float*)d_in[4];
  const float* wv  = (const float*)d_in[5];
  const float* bv  = (const float*)d_in[6];
  const float* wo  = (const float*)d_in[7];
  const float* bo  = (const float*)d_in[8];
  const float* w1  = (const float*)d_in[9];
  const float* b1  = (const float*)d_in[10];
  const float* w2  = (const float*)d_in[11];
  const float* b2  = (const float*)d_in[12];
  const float* g1  = (const float*)d_in[13];
  const float* be1 = (const float*)d_in[14];
  const float* g2  = (const float*)d_in[15];
  const float* be2 = (const float*)d_in[16];
  float* out = (float*)d_out;

  char* ws = (char*)d_ws;
  const size_t MB = 1u << 20;
  bf16* qb    = (bf16*)(ws + 0);         // 16 MiB  [B,H,S,DH]
  bf16* kb    = (bf16*)(ws + 16 * MB);   // 16 MiB  [B,H,S,DH]
  bf16* vvb   = (bf16*)(ws + 32 * MB);   // 16 MiB  [B,H,DH,S]  (transposed!)
  bf16* xb    = (bf16*)(ws + 48 * MB);   // 16 MiB  [B*S, D]
  bf16* hb    = (bf16*)(ws + 0);         // 64 MiB, reuses q/k/v/xb after attn
  bf16* ctx   = (bf16*)(ws + 64 * MB);   // 16 MiB  [B*S, H*DH]
  float* y    = (float*)(ws + 80 * MB);  // 32 MiB  f32 (attn-out, then ffn-out)
  float* x1f  = (float*)(ws + 112 * MB); // 32 MiB  f32 post-LN1
  bf16* x1b   = (bf16*)(ws + 144 * MB);  // 16 MiB  bf16 post-LN1
  bf16* btqkv = (bf16*)(ws + 160 * MB);  // 6 MiB   [3072][1024]
  bf16* wot   = (bf16*)(ws + 166 * MB);  // 2 MiB   [1024][1024]
  bf16* w1t   = (bf16*)(ws + 168 * MB);  // 8 MiB   [4096][1024]
  bf16* w2t   = (bf16*)(ws + 176 * MB);  // 8 MiB   [1024][4096]

  // --- weight/activation conversion ---
  f32_to_bf16_vec<<<8192, 256, 0, stream>>>(x, xb, Bb * Ss * Dd / 4);
  transpose_f32_bf16<<<dim3(2, 32, 16), 256, 0, stream>>>(wq, btqkv + 0 * 1048576,
                                                          Dd, DHh, 65536, 65536);
  transpose_f32_bf16<<<dim3(2, 32, 16), 256, 0, stream>>>(wk, btqkv + 1 * 1048576,
                                                          Dd, DHh, 65536, 65536);
  transpose_f32_bf16<<<dim3(2, 32, 16), 256, 0, stream>>>(wv, btqkv + 2 * 1048576,
                                                          Dd, DHh, 65536, 65536);
  transpose_f32_bf16<<<dim3(32, 32, 1), 256, 0, stream>>>(wo, wot, Hh * DHh, Dd, 0, 0);
  transpose_f32_bf16<<<dim3(128, 32, 1), 256, 0, stream>>>(w1, w1t, Dd, FFf, 0, 0);
  transpose_f32_bf16<<<dim3(32, 128, 1), 256, 0, stream>>>(w2, w2t, FFf, Dd, 0, 0);

  // --- QKV projection (V written transposed per head) ---
  gemm256<EPI_QKV><<<384, 512, 131072, stream>>>(
      xb, btqkv, Bb * Ss, 3 * Hh * DHh, Dd, bq, bk, bv, qb, kb, vvb);

  // --- attention ---
  attn_kernel<<<2048, 256, 0, stream>>>(qb, kb, vvb, ctx);

  // --- output projection ---
  gemm256<EPI_WO><<<128, 512, 131072, stream>>>(
      ctx, wot, Bb * Ss, Dd, Hh * DHh, bo, nullptr, nullptr, y, nullptr, nullptr);

  // --- residual + LN1 ---
  ln_fused<<<Bb * Ss, 256, 0, stream>>>(x, y, g1, be1, x1f, x1b);

  // --- FFN ---
  gemm256<EPI_FFN1><<<512, 512, 131072, stream>>>(
      x1b, w1t, Bb * Ss, FFf, Dd, b1, nullptr, nullptr, hb, nullptr, nullptr);
  gemm256<EPI_FFN2><<<128, 512, 131072, stream>>>(
      hb, w2t, Bb * Ss, Dd, FFf, b2, nullptr, nullptr, y, nullptr, nullptr);

  // --- residual + LN2 -> out ---
  ln_fused<<<Bb * Ss, 256, 0, stream>>>(x1f, y, g2, be2, out, nullptr);
}

// Round 7
// 560.781 us; speedup vs baseline: 1.2489x; 1.1151x over previous
//
#include <hip/hip_runtime.h>
#include <hip/hip_bf16.h>

// Problem constants
#define Bb 8
#define Ss 1024
#define Dd 1024
#define Hh 16
#define DHh 64
#define FFf 4096

typedef __hip_bfloat16 bf16;
typedef __attribute__((ext_vector_type(8))) __bf16 bf16x8;
typedef __attribute__((ext_vector_type(4))) float f32x4;

__device__ __forceinline__ unsigned short f2bu(float f) {
  __hip_bfloat16 h = __float2bfloat16(f);
  return __builtin_bit_cast(unsigned short, h);
}

#define MFMA16(a, b, c) __builtin_amdgcn_mfma_f32_16x16x32_bf16((a), (b), (c), 0, 0, 0)

__device__ __forceinline__ void gl_lds16(const void* g, void* l) {
  __builtin_amdgcn_global_load_lds(
      (const __attribute__((address_space(1))) unsigned int*)g,
      (__attribute__((address_space(3))) unsigned int*)l, 16, 0, 0);
}

// ---------------------------------------------------------------------------
// f32 -> bf16 elementwise convert
// ---------------------------------------------------------------------------
__global__ __launch_bounds__(256) void f32_to_bf16_vec(const float* __restrict__ in,
                                                       bf16* __restrict__ out, int n4) {
  int i = blockIdx.x * 256 + threadIdx.x;
  if (i < n4) {
    float4 v = ((const float4*)in)[i];
    union { unsigned short u[4]; uint2 q; } r;
    r.u[0] = f2bu(v.x); r.u[1] = f2bu(v.y); r.u[2] = f2bu(v.z); r.u[3] = f2bu(v.w);
    ((uint2*)out)[i] = r.q;
  }
}

// ---------------------------------------------------------------------------
// Batched 32x32 LDS-tiled transpose: src f32 [R][C] -> dst bf16 [C][R]
// ---------------------------------------------------------------------------
__global__ __launch_bounds__(256) void transpose_f32_bf16(const float* __restrict__ src,
                                                          bf16* __restrict__ dst,
                                                          int R, int C,
                                                          long sbatch, long dbatch) {
  __shared__ float tile[32][33];
  src += (size_t)blockIdx.z * sbatch;
  dst += (size_t)blockIdx.z * dbatch;
  int c0 = blockIdx.x * 32, r0 = blockIdx.y * 32;
  int tx = threadIdx.x & 31;
  int ty = threadIdx.x >> 5;  // 0..7
#pragma unroll
  for (int kk = 0; kk < 4; ++kk)
    tile[ty + kk * 8][tx] = src[(size_t)(r0 + ty + kk * 8) * C + c0 + tx];
  __syncthreads();
#pragma unroll
  for (int kk = 0; kk < 4; ++kk)
    dst[(size_t)(c0 + ty + kk * 8) * R + r0 + tx] = __float2bfloat16(tile[tx][ty + kk * 8]);
}

// ---------------------------------------------------------------------------
// GEMM (r7): C[M,N] = A[M,K] * Bt[N,K]^T (+bias epilogues)
// 128x128 tile, BK=64 (was 32 in r4: halves barrier-drain events), 4 waves,
// per-wave 64x64 = 4x4 frags, 32 MFMA/wave/tile.
// LDS 32KB: A[128][128B] + B[128][128B], linear rows.
// 3-bit seg swizzle (HW-verified conflict-free in r6): LDS[s] = G[s^(r&7)];
// reads use seg' = (kk*4+ks)^(row&7) -> 8 words/bank = b128 floor.
// Schedule identical to r4: sync; stage (8x gl_lds); sync; read+MFMA.
// ---------------------------------------------------------------------------
enum { EPI_QKV = 0, EPI_WO = 1, EPI_FFN1 = 2, EPI_FFN2 = 3 };

__device__ __forceinline__ void stage_u(const bf16* __restrict__ G, int ldK,
                                        int row0, int kt, int u,
                                        unsigned char* ldsbase, int tid) {
  const int r = u * 32 + (tid >> 3);             // row 0..127 of the tile
  const int seg = (tid & 7) ^ (r & 7);           // inverse-swizzled source seg
  gl_lds16(G + (size_t)(row0 + r) * ldK + kt + seg * 8,
           ldsbase + u * 4096 + (tid >> 6) * 1024);
}

template <int EPI>
__global__ __launch_bounds__(256) void gemm_bt(const bf16* __restrict__ A,
                                               const bf16* __restrict__ Bt,
                                               int M, int N, int K,
                                               const float* __restrict__ bias0,
                                               const float* __restrict__ bias1,
                                               const float* __restrict__ bias2,
                                               void* __restrict__ o0,
                                               void* __restrict__ o1,
                                               void* __restrict__ o2) {
  __shared__ __align__(16) unsigned char sm[32768];  // A: [0,16K), B: [16K,32K)
  const int t = threadIdx.x;
  const int lane = t & 63;
  const int w = t >> 6;       // wave 0..3
  const int wr = w >> 1;      // wave row 0..1
  const int wc = w & 1;       // wave col 0..1
  const int m0 = blockIdx.x * 128;
  const int n0 = blockIdx.y * 128;
  const int rl = lane & 15, ks = lane >> 4;

  f32x4 acc[4][4];
  const f32x4 z4 = {0.f, 0.f, 0.f, 0.f};
#pragma unroll
  for (int i = 0; i < 4; ++i)
#pragma unroll
    for (int j = 0; j < 4; ++j) acc[i][j] = z4;

  for (int kt = 0; kt < K; kt += 64) {
    __syncthreads();
#pragma unroll
    for (int u = 0; u < 4; ++u) stage_u(A, K, m0, kt, u, sm, t);
#pragma unroll
    for (int u = 0; u < 4; ++u) stage_u(Bt, K, n0, kt, u, sm + 16384, t);
    __syncthreads();

    bf16x8 a[4][2], b[4][2];
#pragma unroll
    for (int i = 0; i < 4; ++i) {
#pragma unroll
      for (int kk = 0; kk < 2; ++kk) {
        const int row = wr * 64 + i * 16 + rl;
        a[i][kk] = *(const bf16x8*)(sm + row * 128 + (((kk * 4 + ks) ^ (row & 7)) << 4));
        const int col = wc * 64 + i * 16 + rl;
        b[i][kk] = *(const bf16x8*)(sm + 16384 + col * 128 + (((kk * 4 + ks) ^ (col & 7)) << 4));
      }
    }
#pragma unroll
    for (int i = 0; i < 4; ++i)
#pragma unroll
      for (int j = 0; j < 4; ++j)
#pragma unroll
        for (int kk = 0; kk < 2; ++kk)
          acc[i][j] = MFMA16(a[i][kk], b[j][kk], acc[i][j]);
  }

  // Epilogue. C/D frag layout: row = (lane>>4)*4 + p, col = lane&15.
  const int rbase = ks * 4;
  if constexpr (EPI == EPI_QKV) {
    const int which = n0 >> 10;  // 0=q,1=k,2=v (128-tile never straddles 1024)
    const float* bias = which == 0 ? bias0 : (which == 1 ? bias1 : bias2);
    bf16* dst = (bf16*)(which == 0 ? o0 : (which == 1 ? o1 : o2));
#pragma unroll
    for (int i = 0; i < 4; ++i) {
#pragma unroll
      for (int j = 0; j < 4; ++j) {
        const int gcol = n0 + wc * 64 + j * 16 + rl;
        const int cc = gcol & 1023;
        const int hh = cc >> 6, e = cc & 63;
        const float bval = bias[cc];
#pragma unroll
        for (int p = 0; p < 4; ++p) {
          const int grow = m0 + wr * 64 + i * 16 + rbase + p;
          const int bidx = grow >> 10, s = grow & 1023;
          if (which == 2) {
            // V stored transposed per head: [B,H,DH,S]
            dst[(((size_t)bidx * Hh + hh) * DHh + e) * Ss + s] =
                __float2bfloat16(acc[i][j][p] + bval);
          } else {
            dst[(((size_t)bidx * Hh + hh) * Ss + s) * DHh + e] =
                __float2bfloat16(acc[i][j][p] + bval);
          }
        }
      }
    }
  } else if constexpr (EPI == EPI_WO || EPI == EPI_FFN2) {
    float* dst = (float*)o0;
#pragma unroll
    for (int i = 0; i < 4; ++i) {
#pragma unroll
      for (int j = 0; j < 4; ++j) {
        const int gcol = n0 + wc * 64 + j * 16 + rl;
        const float bval = bias0[gcol];
#pragma unroll
        for (int p = 0; p < 4; ++p) {
          const int grow = m0 + wr * 64 + i * 16 + rbase + p;
          dst[(size_t)grow * N + gcol] = acc[i][j][p] + bval;
        }
      }
    }
  } else {  // EPI_FFN1: ReLU -> bf16
    bf16* dst = (bf16*)o0;
#pragma unroll
    for (int i = 0; i < 4; ++i) {
#pragma unroll
      for (int j = 0; j < 4; ++j) {
        const int gcol = n0 + wc * 64 + j * 16 + rl;
        const float bval = bias0[gcol];
#pragma unroll
        for (int p = 0; p < 4; ++p) {
          const int grow = m0 + wr * 64 + i * 16 + rbase + p;
          dst[(size_t)grow * N + gcol] =
              __float2bfloat16(fmaxf(acc[i][j][p] + bval, 0.f));
        }
      }
    }
  }
}

// ---------------------------------------------------------------------------
// Flash attention v3: r4 structure + T14 async reg-staging.
// Tile t+1 is loaded global->regs while tile t computes; regs->LDS via
// swizzled ds_write after the barrier (same LDS image as gl_lds path:
// LDS[s^(r&7)] = G[s]). LDS size unchanged -> occupancy preserved.
// ---------------------------------------------------------------------------
__global__ __launch_bounds__(256) void attn_kernel(const bf16* __restrict__ q,
                                                   const bf16* __restrict__ k,
                                                   const bf16* __restrict__ v,
                                                   bf16* __restrict__ ctx) {
  __shared__ __align__(16) unsigned short Kl[64 * 64];
  __shared__ __align__(16) unsigned short Vt[64 * 64];
  __shared__ __align__(16) unsigned short Pl[4 * 16 * 72];

  const int bid = blockIdx.x;
  const int xcd = bid & 7;
  const int s8 = bid >> 3;             // 0..255
  const int hg = xcd + 8 * (s8 >> 4);  // 0..127  (b*16+h)
  const int qi = s8 & 15;
  const int b = hg >> 4, h = hg & 15;
  const int q0 = qi * 64;
  const size_t head = (size_t)hg << 16;  // hg * S * DH
  const bf16* Qp = q + head;
  const bf16* Kp = k + head;
  const bf16* Vp = v + head;  // per-head [DH][S]

  const int t = threadIdx.x;
  const int w = t >> 6;
  const int lane = t & 63;
  const int rl = lane & 15;
  const int ks = lane >> 4;  // 0..3
  const int rx = rl & 7;

  const int qrow = q0 + w * 16 + rl;
  const bf16x8 aq0 = *(const bf16x8*)(Qp + (size_t)qrow * 64 + ks * 8);
  const bf16x8 aq1 = *(const bf16x8*)(Qp + (size_t)qrow * 64 + 32 + ks * 8);

  f32x4 o[4];
  const f32x4 z4 = {0.f, 0.f, 0.f, 0.f};
#pragma unroll
  for (int c = 0; c < 4; ++c) o[c] = z4;
  float m4[4] = {-1e30f, -1e30f, -1e30f, -1e30f};
  float l4[4] = {0.f, 0.f, 0.f, 0.f};

  // reg-staging assignment: thread t covers row rt = t>>2 (0..63),
  // segs st (0..3) and st+4 -> two 16B loads per matrix, coalesced 64B/4 lanes
  const int rt = t >> 2;
  const int st = t & 3;
  const int wof0 = rt * 64 + ((st ^ (rt & 7)) << 3);        // swizzled LDS short-offset
  const int wof1 = rt * 64 + (((st + 4) ^ (rt & 7)) << 3);
  unsigned short* Pw = Pl + w * 16 * 72;
  const float scale = 0.125f;  // 1/sqrt(64)

  // preload tile 0 into regs
  bf16x8 kr0 = *(const bf16x8*)(Kp + (size_t)rt * 64 + st * 8);
  bf16x8 kr1 = *(const bf16x8*)(Kp + (size_t)rt * 64 + (st + 4) * 8);
  bf16x8 vr0 = *(const bf16x8*)(Vp + (size_t)rt * Ss + st * 8);
  bf16x8 vr1 = *(const bf16x8*)(Vp + (size_t)rt * Ss + (st + 4) * 8);

  for (int kv0 = 0; kv0 < Ss; kv0 += 64) {
    __syncthreads();
    // write staged regs -> LDS (compiler inserts vmcnt waits for the regs)
    *(bf16x8*)(Kl + wof0) = kr0;
    *(bf16x8*)(Kl + wof1) = kr1;
    *(bf16x8*)(Vt + wof0) = vr0;
    *(bf16x8*)(Vt + wof1) = vr1;
    // issue next tile's loads early; they fly under this tile's compute
    if (kv0 + 64 < Ss) {
      kr0 = *(const bf16x8*)(Kp + (size_t)(kv0 + 64 + rt) * 64 + st * 8);
      kr1 = *(const bf16x8*)(Kp + (size_t)(kv0 + 64 + rt) * 64 + (st + 4) * 8);
      vr0 = *(const bf16x8*)(Vp + (size_t)rt * Ss + kv0 + 64 + st * 8);
      vr1 = *(const bf16x8*)(Vp + (size_t)rt * Ss + kv0 + 64 + (st + 4) * 8);
    }
    __syncthreads();

    f32x4 s4[4];
#pragma unroll
    for (int f = 0; f < 4; ++f) s4[f] = z4;
#pragma unroll
    for (int f = 0; f < 4; ++f) {
      const int row = f * 16 + rl;
      const bf16x8 b0 = *(const bf16x8*)(Kl + row * 64 + (ks ^ rx) * 8);
      const bf16x8 b1 = *(const bf16x8*)(Kl + row * 64 + ((4 + ks) ^ rx) * 8);
      s4[f] = MFMA16(aq0, b0, s4[f]);
      s4[f] = MFMA16(aq1, b1, s4[f]);
    }

    float mx[4], sm[4];
#pragma unroll
    for (int j = 0; j < 4; ++j) {
      s4[0][j] *= scale; s4[1][j] *= scale; s4[2][j] *= scale; s4[3][j] *= scale;
      mx[j] = fmaxf(fmaxf(s4[0][j], s4[1][j]), fmaxf(s4[2][j], s4[3][j]));
    }
#pragma unroll
    for (int mm = 1; mm < 16; mm <<= 1)
#pragma unroll
      for (int j = 0; j < 4; ++j) mx[j] = fmaxf(mx[j], __shfl_xor(mx[j], mm, 64));
#pragma unroll
    for (int j = 0; j < 4; ++j) {
      const float mn = fmaxf(m4[j], mx[j]);
      const float corr = __expf(m4[j] - mn);
      m4[j] = mn;
#pragma unroll
      for (int f = 0; f < 4; ++f) s4[f][j] = __expf(s4[f][j] - mn);
      sm[j] = (s4[0][j] + s4[1][j]) + (s4[2][j] + s4[3][j]);
      l4[j] *= corr;
#pragma unroll
      for (int c = 0; c < 4; ++c) o[c][j] *= corr;
    }
#pragma unroll
    for (int mm = 1; mm < 16; mm <<= 1)
#pragma unroll
      for (int j = 0; j < 4; ++j) sm[j] += __shfl_xor(sm[j], mm, 64);
#pragma unroll
    for (int j = 0; j < 4; ++j) l4[j] += sm[j];

#pragma unroll
    for (int f = 0; f < 4; ++f)
#pragma unroll
      for (int j = 0; j < 4; ++j)
        Pw[(ks * 4 + j) * 72 + f * 16 + rl] = f2bu(s4[f][j]);
    asm volatile("s_waitcnt lgkmcnt(0)" ::: "memory");
    __builtin_amdgcn_sched_barrier(0);
    const bf16x8 pa0 = *(const bf16x8*)(Pw + rl * 72 + ks * 8);
    const bf16x8 pa1 = *(const bf16x8*)(Pw + rl * 72 + 32 + ks * 8);

#pragma unroll
    for (int c = 0; c < 4; ++c) {
      const int row = c * 16 + rl;
      const bf16x8 v0 = *(const bf16x8*)(Vt + row * 64 + (ks ^ rx) * 8);
      const bf16x8 v1 = *(const bf16x8*)(Vt + row * 64 + ((4 + ks) ^ rx) * 8);
      o[c] = MFMA16(pa0, v0, o[c]);
      o[c] = MFMA16(pa1, v1, o[c]);
    }
  }

  float inv[4];
#pragma unroll
  for (int j = 0; j < 4; ++j) inv[j] = 1.0f / l4[j];
#pragma unroll
  for (int c = 0; c < 4; ++c) {
#pragma unroll
    for (int j = 0; j < 4; ++j) {
      const int sq = q0 + w * 16 + ks * 4 + j;
      const int dh = c * 16 + rl;
      ctx[(((size_t)b * Ss + sq) * Hh + h) * DHh + dh] =
          __float2bfloat16(o[c][j] * inv[j]);
    }
  }
}

// ---------------------------------------------------------------------------
// Fused residual + LayerNorm
// ---------------------------------------------------------------------------
__global__ __launch_bounds__(256) void ln_fused(const float* __restrict__ a,
                                                const float* __restrict__ bsrc,
                                                const float* __restrict__ g,
                                                const float* __restrict__ be,
                                                float* __restrict__ of,
                                                bf16* __restrict__ ob) {
  const int row = blockIdx.x, t = threadIdx.x;
  const float4 va = ((const float4*)(a + (size_t)row * Dd))[t];
  const float4 vb = ((const float4*)(bsrc + (size_t)row * Dd))[t];
  const float x0 = va.x + vb.x, x1 = va.y + vb.y, x2 = va.z + vb.z, x3 = va.w + vb.w;
  float s = x0 + x1 + x2 + x3;
  float qq = x0 * x0 + x1 * x1 + x2 * x2 + x3 * x3;
#pragma unroll
  for (int m = 1; m < 64; m <<= 1) {
    s += __shfl_xor(s, m, 64);
    qq += __shfl_xor(qq, m, 64);
  }
  __shared__ float ss[4], sq2[4];
  if ((t & 63) == 0) {
    ss[t >> 6] = s;
    sq2[t >> 6] = qq;
  }
  __syncthreads();
  s = ss[0] + ss[1] + ss[2] + ss[3];
  qq = sq2[0] + sq2[1] + sq2[2] + sq2[3];
  const float mu = s * (1.0f / Dd);
  const float var = qq * (1.0f / Dd) - mu * mu;
  const float rs = rsqrtf(var + 1e-5f);
  const float4 gv = ((const float4*)g)[t];
  const float4 bv = ((const float4*)be)[t];
  const float y0 = (x0 - mu) * rs * gv.x + bv.x;
  const float y1 = (x1 - mu) * rs * gv.y + bv.y;
  const float y2 = (x2 - mu) * rs * gv.z + bv.z;
  const float y3 = (x3 - mu) * rs * gv.w + bv.w;
  if (of) ((float4*)(of + (size_t)row * Dd))[t] = make_float4(y0, y1, y2, y3);
  if (ob) {
    union { unsigned short u[4]; uint2 qv; } r;
    r.u[0] = f2bu(y0); r.u[1] = f2bu(y1); r.u[2] = f2bu(y2); r.u[3] = f2bu(y3);
    ((uint2*)(ob + (size_t)row * Dd))[t] = r.qv;
  }
}

// ---------------------------------------------------------------------------
extern "C" void kernel_launch(void* const* d_in, const int* in_sizes, int n_in,
                              void* d_out, int out_size, void* d_ws, size_t ws_size,
                              hipStream_t stream) {
  const float* x   = (const float*)d_in[0];
  const float* wq  = (const float*)d_in[1];
  const float* bq  = (const float*)d_in[2];
  const float* wk  = (const float*)d_in[3];
  const float* bk  = (const float*)d_in[4];
  const float* wv  = (const float*)d_in[5];
  const float* bv  = (const float*)d_in[6];
  const float* wo  = (const float*)d_in[7];
  const float* bo  = (const float*)d_in[8];
  const float* w1  = (const float*)d_in[9];
  const float* b1  = (const float*)d_in[10];
  const float* w2  = (const float*)d_in[11];
  const float* b2  = (const float*)d_in[12];
  const float* g1  = (const float*)d_in[13];
  const float* be1 = (const float*)d_in[14];
  const float* g2  = (const float*)d_in[15];
  const float* be2 = (const float*)d_in[16];
  float* out = (float*)d_out;

  char* ws = (char*)d_ws;
  const size_t MB = 1u << 20;
  bf16* qb    = (bf16*)(ws + 0);         // 16 MiB  [B,H,S,DH]
  bf16* kb    = (bf16*)(ws + 16 * MB);   // 16 MiB  [B,H,S,DH]
  bf16* vvb   = (bf16*)(ws + 32 * MB);   // 16 MiB  [B,H,DH,S]  (transposed!)
  bf16* xb    = (bf16*)(ws + 48 * MB);   // 16 MiB  [B*S, D]
  bf16* hb    = (bf16*)(ws + 0);         // 64 MiB, reuses q/k/v/xb after attn
  bf16* ctx   = (bf16*)(ws + 64 * MB);   // 16 MiB  [B*S, H*DH]
  float* y    = (float*)(ws + 80 * MB);  // 32 MiB  f32 (attn-out, then ffn-out)
  float* x1f  = (float*)(ws + 112 * MB); // 32 MiB  f32 post-LN1
  bf16* x1b   = (bf16*)(ws + 144 * MB);  // 16 MiB  bf16 post-LN1
  bf16* btqkv = (bf16*)(ws + 160 * MB);  // 6 MiB   [3072][1024]
  bf16* wot   = (bf16*)(ws + 166 * MB);  // 2 MiB   [1024][1024]
  bf16* w1t   = (bf16*)(ws + 168 * MB);  // 8 MiB   [4096][1024]
  bf16* w2t   = (bf16*)(ws + 176 * MB);  // 8 MiB   [1024][4096]

  // --- weight/activation conversion ---
  f32_to_bf16_vec<<<8192, 256, 0, stream>>>(x, xb, Bb * Ss * Dd / 4);
  transpose_f32_bf16<<<dim3(2, 32, 16), 256, 0, stream>>>(wq, btqkv + 0 * 1048576,
                                                          Dd, DHh, 65536, 65536);
  transpose_f32_bf16<<<dim3(2, 32, 16), 256, 0, stream>>>(wk, btqkv + 1 * 1048576,
                                                          Dd, DHh, 65536, 65536);
  transpose_f32_bf16<<<dim3(2, 32, 16), 256, 0, stream>>>(wv, btqkv + 2 * 1048576,
                                                          Dd, DHh, 65536, 65536);
  transpose_f32_bf16<<<dim3(32, 32, 1), 256, 0, stream>>>(wo, wot, Hh * DHh, Dd, 0, 0);
  transpose_f32_bf16<<<dim3(128, 32, 1), 256, 0, stream>>>(w1, w1t, Dd, FFf, 0, 0);
  transpose_f32_bf16<<<dim3(32, 128, 1), 256, 0, stream>>>(w2, w2t, FFf, Dd, 0, 0);

  // --- QKV projection (V written transposed per head) ---
  gemm_bt<EPI_QKV><<<dim3(64, 24), 256, 0, stream>>>(
      xb, btqkv, Bb * Ss, 3 * Hh * DHh, Dd, bq, bk, bv, qb, kb, vvb);

  // --- attention ---
  attn_kernel<<<2048, 256, 0, stream>>>(qb, kb, vvb, ctx);

  // --- output projection ---
  gemm_bt<EPI_WO><<<dim3(64, 8), 256, 0, stream>>>(
      ctx, wot, Bb * Ss, Dd, Hh * DHh, bo, nullptr, nullptr, y, nullptr, nullptr);

  // --- residual + LN1 ---
  ln_fused<<<Bb * Ss, 256, 0, stream>>>(x, y, g1, be1, x1f, x1b);

  // --- FFN ---
  gemm_bt<EPI_FFN1><<<dim3(64, 32), 256, 0, stream>>>(
      x1b, w1t, Bb * Ss, FFf, Dd, b1, nullptr, nullptr, hb, nullptr, nullptr);
  gemm_bt<EPI_FFN2><<<dim3(64, 8), 256, 0, stream>>>(
      hb, w2t, Bb * Ss, Dd, FFf, b2, nullptr, nullptr, y, nullptr, nullptr);

  // --- residual + LN2 -> out ---
  ln_fused<<<Bb * Ss, 256, 0, stream>>>(x1f, y, g2, be2, out, nullptr);
}

// Round 8
// 533.453 us; speedup vs baseline: 1.3128x; 1.0512x over previous
//
#include <hip/hip_runtime.h>
#include <hip/hip_bf16.h>

// Problem constants
#define Bb 8
#define Ss 1024
#define Dd 1024
#define Hh 16
#define DHh 64
#define FFf 4096

typedef __hip_bfloat16 bf16;
typedef __attribute__((ext_vector_type(8))) __bf16 bf16x8;
typedef __attribute__((ext_vector_type(4))) float f32x4;

__device__ __forceinline__ unsigned short f2bu(float f) {
  __hip_bfloat16 h = __float2bfloat16(f);
  return __builtin_bit_cast(unsigned short, h);
}

#define MFMA16(a, b, c) __builtin_amdgcn_mfma_f32_16x16x32_bf16((a), (b), (c), 0, 0, 0)

__device__ __forceinline__ void gl_lds16(const void* g, void* l) {
  __builtin_amdgcn_global_load_lds(
      (const __attribute__((address_space(1))) unsigned int*)g,
      (__attribute__((address_space(3))) unsigned int*)l, 16, 0, 0);
}

// ---------------------------------------------------------------------------
// f32 -> bf16 elementwise convert
// ---------------------------------------------------------------------------
__global__ __launch_bounds__(256) void f32_to_bf16_vec(const float* __restrict__ in,
                                                       bf16* __restrict__ out, int n4) {
  int i = blockIdx.x * 256 + threadIdx.x;
  if (i < n4) {
    float4 v = ((const float4*)in)[i];
    union { unsigned short u[4]; uint2 q; } r;
    r.u[0] = f2bu(v.x); r.u[1] = f2bu(v.y); r.u[2] = f2bu(v.z); r.u[3] = f2bu(v.w);
    ((uint2*)out)[i] = r.q;
  }
}

// ---------------------------------------------------------------------------
// Batched 32x32 LDS-tiled transpose: src f32 [R][C] -> dst bf16 [C][R]
// ---------------------------------------------------------------------------
__global__ __launch_bounds__(256) void transpose_f32_bf16(const float* __restrict__ src,
                                                          bf16* __restrict__ dst,
                                                          int R, int C,
                                                          long sbatch, long dbatch) {
  __shared__ float tile[32][33];
  src += (size_t)blockIdx.z * sbatch;
  dst += (size_t)blockIdx.z * dbatch;
  int c0 = blockIdx.x * 32, r0 = blockIdx.y * 32;
  int tx = threadIdx.x & 31;
  int ty = threadIdx.x >> 5;  // 0..7
#pragma unroll
  for (int kk = 0; kk < 4; ++kk)
    tile[ty + kk * 8][tx] = src[(size_t)(r0 + ty + kk * 8) * C + c0 + tx];
  __syncthreads();
#pragma unroll
  for (int kk = 0; kk < 4; ++kk)
    dst[(size_t)(c0 + ty + kk * 8) * R + r0 + tx] = __float2bfloat16(tile[tx][ty + kk * 8]);
}

// ---------------------------------------------------------------------------
// GEMM (r7, unchanged): 128x128 tile, BK=64, 3-bit seg swizzle, gl_lds.
// ---------------------------------------------------------------------------
enum { EPI_QKV = 0, EPI_WO = 1, EPI_FFN1 = 2, EPI_FFN2 = 3 };

__device__ __forceinline__ void stage_u(const bf16* __restrict__ G, int ldK,
                                        int row0, int kt, int u,
                                        unsigned char* ldsbase, int tid) {
  const int r = u * 32 + (tid >> 3);             // row 0..127 of the tile
  const int seg = (tid & 7) ^ (r & 7);           // inverse-swizzled source seg
  gl_lds16(G + (size_t)(row0 + r) * ldK + kt + seg * 8,
           ldsbase + u * 4096 + (tid >> 6) * 1024);
}

template <int EPI>
__global__ __launch_bounds__(256) void gemm_bt(const bf16* __restrict__ A,
                                               const bf16* __restrict__ Bt,
                                               int M, int N, int K,
                                               const float* __restrict__ bias0,
                                               const float* __restrict__ bias1,
                                               const float* __restrict__ bias2,
                                               void* __restrict__ o0,
                                               void* __restrict__ o1,
                                               void* __restrict__ o2) {
  __shared__ __align__(16) unsigned char sm[32768];  // A: [0,16K), B: [16K,32K)
  const int t = threadIdx.x;
  const int lane = t & 63;
  const int w = t >> 6;       // wave 0..3
  const int wr = w >> 1;      // wave row 0..1
  const int wc = w & 1;       // wave col 0..1
  const int m0 = blockIdx.x * 128;
  const int n0 = blockIdx.y * 128;
  const int rl = lane & 15, ks = lane >> 4;

  f32x4 acc[4][4];
  const f32x4 z4 = {0.f, 0.f, 0.f, 0.f};
#pragma unroll
  for (int i = 0; i < 4; ++i)
#pragma unroll
    for (int j = 0; j < 4; ++j) acc[i][j] = z4;

  for (int kt = 0; kt < K; kt += 64) {
    __syncthreads();
#pragma unroll
    for (int u = 0; u < 4; ++u) stage_u(A, K, m0, kt, u, sm, t);
#pragma unroll
    for (int u = 0; u < 4; ++u) stage_u(Bt, K, n0, kt, u, sm + 16384, t);
    __syncthreads();

    bf16x8 a[4][2], b[4][2];
#pragma unroll
    for (int i = 0; i < 4; ++i) {
#pragma unroll
      for (int kk = 0; kk < 2; ++kk) {
        const int row = wr * 64 + i * 16 + rl;
        a[i][kk] = *(const bf16x8*)(sm + row * 128 + (((kk * 4 + ks) ^ (row & 7)) << 4));
        const int col = wc * 64 + i * 16 + rl;
        b[i][kk] = *(const bf16x8*)(sm + 16384 + col * 128 + (((kk * 4 + ks) ^ (col & 7)) << 4));
      }
    }
#pragma unroll
    for (int i = 0; i < 4; ++i)
#pragma unroll
      for (int j = 0; j < 4; ++j)
#pragma unroll
        for (int kk = 0; kk < 2; ++kk)
          acc[i][j] = MFMA16(a[i][kk], b[j][kk], acc[i][j]);
  }

  // Epilogue. C/D frag layout: row = (lane>>4)*4 + p, col = lane&15.
  const int rbase = ks * 4;
  if constexpr (EPI == EPI_QKV) {
    const int which = n0 >> 10;  // 0=q,1=k,2=v (128-tile never straddles 1024)
    const float* bias = which == 0 ? bias0 : (which == 1 ? bias1 : bias2);
    bf16* dst = (bf16*)(which == 0 ? o0 : (which == 1 ? o1 : o2));
#pragma unroll
    for (int i = 0; i < 4; ++i) {
#pragma unroll
      for (int j = 0; j < 4; ++j) {
        const int gcol = n0 + wc * 64 + j * 16 + rl;
        const int cc = gcol & 1023;
        const int hh = cc >> 6, e = cc & 63;
        const float bval = bias[cc];
#pragma unroll
        for (int p = 0; p < 4; ++p) {
          const int grow = m0 + wr * 64 + i * 16 + rbase + p;
          const int bidx = grow >> 10, s = grow & 1023;
          if (which == 2) {
            // V stored transposed per head: [B,H,DH,S]
            dst[(((size_t)bidx * Hh + hh) * DHh + e) * Ss + s] =
                __float2bfloat16(acc[i][j][p] + bval);
          } else {
            dst[(((size_t)bidx * Hh + hh) * Ss + s) * DHh + e] =
                __float2bfloat16(acc[i][j][p] + bval);
          }
        }
      }
    }
  } else if constexpr (EPI == EPI_WO || EPI == EPI_FFN2) {
    float* dst = (float*)o0;
#pragma unroll
    for (int i = 0; i < 4; ++i) {
#pragma unroll
      for (int j = 0; j < 4; ++j) {
        const int gcol = n0 + wc * 64 + j * 16 + rl;
        const float bval = bias0[gcol];
#pragma unroll
        for (int p = 0; p < 4; ++p) {
          const int grow = m0 + wr * 64 + i * 16 + rbase + p;
          dst[(size_t)grow * N + gcol] = acc[i][j][p] + bval;
        }
      }
    }
  } else {  // EPI_FFN1: ReLU -> bf16
    bf16* dst = (bf16*)o0;
#pragma unroll
    for (int i = 0; i < 4; ++i) {
#pragma unroll
      for (int j = 0; j < 4; ++j) {
        const int gcol = n0 + wc * 64 + j * 16 + rl;
        const float bval = bias0[gcol];
#pragma unroll
        for (int p = 0; p < 4; ++p) {
          const int grow = m0 + wr * 64 + i * 16 + rbase + p;
          dst[(size_t)grow * N + gcol] =
              __float2bfloat16(fmaxf(acc[i][j][p] + bval, 0.f));
        }
      }
    }
  }
}

// ---------------------------------------------------------------------------
// Flash attention v4: KVBLK=128, gl_lds staging (T14 reverted), defer-max.
// K [128][64] staged linear w/ 3-bit seg swizzle; V^T [64][128] staged linear
// w/ 4-bit seg swizzle sw^=(d&7) (256B rows alias 16-way without it).
// P per-wave [16][136] shorts. 8 kv-tiles (vs 16) halve per-kv softmax cost;
// defer-max skips the O/l rescale unless the running max grows by >8.
// ---------------------------------------------------------------------------
__global__ __launch_bounds__(256) void attn_kernel(const bf16* __restrict__ q,
                                                   const bf16* __restrict__ k,
                                                   const bf16* __restrict__ v,
                                                   bf16* __restrict__ ctx) {
  __shared__ __align__(16) unsigned short Kl[128 * 64];   // 16KB
  __shared__ __align__(16) unsigned short Vt[64 * 128];   // 16KB
  __shared__ __align__(16) unsigned short Pl[4 * 16 * 136];  // 17KB

  const int bid = blockIdx.x;
  const int xcd = bid & 7;
  const int s8 = bid >> 3;             // 0..255
  const int hg = xcd + 8 * (s8 >> 4);  // 0..127  (b*16+h)
  const int qi = s8 & 15;
  const int b = hg >> 4, h = hg & 15;
  const int q0 = qi * 64;
  const size_t head = (size_t)hg << 16;  // hg * S * DH
  const bf16* Qp = q + head;
  const bf16* Kp = k + head;
  const bf16* Vp = v + head;  // per-head [DH][S]

  const int t = threadIdx.x;
  const int w = t >> 6;
  const int lane = t & 63;
  const int rl = lane & 15;
  const int ks = lane >> 4;  // 0..3

  const int qrow = q0 + w * 16 + rl;
  const bf16x8 aq0 = *(const bf16x8*)(Qp + (size_t)qrow * 64 + ks * 8);
  const bf16x8 aq1 = *(const bf16x8*)(Qp + (size_t)qrow * 64 + 32 + ks * 8);

  f32x4 o[4];
  const f32x4 z4 = {0.f, 0.f, 0.f, 0.f};
#pragma unroll
  for (int c = 0; c < 4; ++c) o[c] = z4;
  float m4[4] = {-1e30f, -1e30f, -1e30f, -1e30f};
  float l4[4] = {0.f, 0.f, 0.f, 0.f};

  unsigned short* Pw = Pl + w * 16 * 136;
  const float scale = 0.125f;  // 1/sqrt(64)

  // staging lane decomposition
  const int kr8 = lane >> 3, ksg = lane & 7;    // K: 8 rows/wave-issue
  const int vr4 = lane >> 4, vsg = lane & 15;   // V: 4 rows/wave-issue

  for (int kv0 = 0; kv0 < Ss; kv0 += 128) {
    __syncthreads();
    // stage K[kv0..+127][0..63]: 4 issues x (32 rows: u*32 + w*8 + kr8)
#pragma unroll
    for (int u = 0; u < 4; ++u) {
      const int row = u * 32 + w * 8 + kr8;
      gl_lds16(Kp + (size_t)(kv0 + row) * 64 + (ksg ^ (row & 7)) * 8,
               Kl + u * 2048 + w * 512);
    }
    // stage V^T[0..63][kv0..+127]: 4 issues x (16 rows: u*16 + w*4 + vr4)
#pragma unroll
    for (int u = 0; u < 4; ++u) {
      const int d = u * 16 + w * 4 + vr4;
      gl_lds16(Vp + (size_t)d * Ss + kv0 + ((vsg ^ (d & 7)) * 8),
               Vt + u * 2048 + w * 512);
    }
    __syncthreads();

    // QK^T: S[16q][128kv] = 8 C-frags
    f32x4 s4[8];
#pragma unroll
    for (int f = 0; f < 8; ++f) s4[f] = z4;
#pragma unroll
    for (int f = 0; f < 8; ++f) {
      const int row = f * 16 + rl;
      const bf16x8 b0 = *(const bf16x8*)(Kl + row * 64 + ((ks ^ (row & 7)) * 8));
      const bf16x8 b1 = *(const bf16x8*)(Kl + row * 64 + (((4 + ks) ^ (row & 7)) * 8));
      s4[f] = MFMA16(aq0, b0, s4[f]);
      s4[f] = MFMA16(aq1, b1, s4[f]);
    }

    // online softmax, defer-max (T13): skip rescale unless max grows > 8
    float mx[4], sm[4];
#pragma unroll
    for (int j = 0; j < 4; ++j) {
      float m01 = fmaxf(s4[0][j], s4[1][j]), m23 = fmaxf(s4[2][j], s4[3][j]);
      float m45 = fmaxf(s4[4][j], s4[5][j]), m67 = fmaxf(s4[6][j], s4[7][j]);
      mx[j] = fmaxf(fmaxf(m01, m23), fmaxf(m45, m67)) * scale;
    }
#pragma unroll
    for (int mm = 1; mm < 16; mm <<= 1)
#pragma unroll
      for (int j = 0; j < 4; ++j) mx[j] = fmaxf(mx[j], __shfl_xor(mx[j], mm, 64));
    const int nogrow = (mx[0] <= m4[0] + 8.f) && (mx[1] <= m4[1] + 8.f) &&
                       (mx[2] <= m4[2] + 8.f) && (mx[3] <= m4[3] + 8.f);
    if (!__all(nogrow)) {
#pragma unroll
      for (int j = 0; j < 4; ++j) {
        const float mn = fmaxf(m4[j], mx[j]);
        const float corr = __expf(m4[j] - mn);
        m4[j] = mn;
        l4[j] *= corr;
#pragma unroll
        for (int c = 0; c < 4; ++c) o[c][j] *= corr;
      }
    }
#pragma unroll
    for (int j = 0; j < 4; ++j) {
#pragma unroll
      for (int f = 0; f < 8; ++f) s4[f][j] = __expf(s4[f][j] * scale - m4[j]);
      sm[j] = ((s4[0][j] + s4[1][j]) + (s4[2][j] + s4[3][j])) +
              ((s4[4][j] + s4[5][j]) + (s4[6][j] + s4[7][j]));
    }
#pragma unroll
    for (int mm = 1; mm < 16; mm <<= 1)
#pragma unroll
      for (int j = 0; j < 4; ++j) sm[j] += __shfl_xor(sm[j], mm, 64);
#pragma unroll
    for (int j = 0; j < 4; ++j) l4[j] += sm[j];

    // P (C-layout) -> per-wave LDS [16][136] -> 4 A-frags
#pragma unroll
    for (int f = 0; f < 8; ++f)
#pragma unroll
      for (int j = 0; j < 4; ++j)
        Pw[(ks * 4 + j) * 136 + f * 16 + rl] = f2bu(s4[f][j]);
    asm volatile("s_waitcnt lgkmcnt(0)" ::: "memory");
    __builtin_amdgcn_sched_barrier(0);
    bf16x8 pa[4];
#pragma unroll
    for (int cc = 0; cc < 4; ++cc)
      pa[cc] = *(const bf16x8*)(Pw + rl * 136 + cc * 32 + ks * 8);

    // PV: out[16q][64d] += P[16q][128kv] * V[128kv][64d]
#pragma unroll
    for (int c = 0; c < 4; ++c) {
      const int d = c * 16 + rl;
#pragma unroll
      for (int cc = 0; cc < 4; ++cc) {
        const bf16x8 vb = *(const bf16x8*)(Vt + d * 128 + (((cc * 4 + ks) ^ (d & 7)) * 8));
        o[c] = MFMA16(pa[cc], vb, o[c]);
      }
    }
  }

  float inv[4];
#pragma unroll
  for (int j = 0; j < 4; ++j) inv[j] = 1.0f / l4[j];
#pragma unroll
  for (int c = 0; c < 4; ++c) {
#pragma unroll
    for (int j = 0; j < 4; ++j) {
      const int sq = q0 + w * 16 + ks * 4 + j;
      const int dh = c * 16 + rl;
      ctx[(((size_t)b * Ss + sq) * Hh + h) * DHh + dh] =
          __float2bfloat16(o[c][j] * inv[j]);
    }
  }
}

// ---------------------------------------------------------------------------
// Fused residual + LayerNorm
// ---------------------------------------------------------------------------
__global__ __launch_bounds__(256) void ln_fused(const float* __restrict__ a,
                                                const float* __restrict__ bsrc,
                                                const float* __restrict__ g,
                                                const float* __restrict__ be,
                                                float* __restrict__ of,
                                                bf16* __restrict__ ob) {
  const int row = blockIdx.x, t = threadIdx.x;
  const float4 va = ((const float4*)(a + (size_t)row * Dd))[t];
  const float4 vb = ((const float4*)(bsrc + (size_t)row * Dd))[t];
  const float x0 = va.x + vb.x, x1 = va.y + vb.y, x2 = va.z + vb.z, x3 = va.w + vb.w;
  float s = x0 + x1 + x2 + x3;
  float qq = x0 * x0 + x1 * x1 + x2 * x2 + x3 * x3;
#pragma unroll
  for (int m = 1; m < 64; m <<= 1) {
    s += __shfl_xor(s, m, 64);
    qq += __shfl_xor(qq, m, 64);
  }
  __shared__ float ss[4], sq2[4];
  if ((t & 63) == 0) {
    ss[t >> 6] = s;
    sq2[t >> 6] = qq;
  }
  __syncthreads();
  s = ss[0] + ss[1] + ss[2] + ss[3];
  qq = sq2[0] + sq2[1] + sq2[2] + sq2[3];
  const float mu = s * (1.0f / Dd);
  const float var = qq * (1.0f / Dd) - mu * mu;
  const float rs = rsqrtf(var + 1e-5f);
  const float4 gv = ((const float4*)g)[t];
  const float4 bv = ((const float4*)be)[t];
  const float y0 = (x0 - mu) * rs * gv.x + bv.x;
  const float y1 = (x1 - mu) * rs * gv.y + bv.y;
  const float y2 = (x2 - mu) * rs * gv.z + bv.z;
  const float y3 = (x3 - mu) * rs * gv.w + bv.w;
  if (of) ((float4*)(of + (size_t)row * Dd))[t] = make_float4(y0, y1, y2, y3);
  if (ob) {
    union { unsigned short u[4]; uint2 qv; } r;
    r.u[0] = f2bu(y0); r.u[1] = f2bu(y1); r.u[2] = f2bu(y2); r.u[3] = f2bu(y3);
    ((uint2*)(ob + (size_t)row * Dd))[t] = r.qv;
  }
}

// ---------------------------------------------------------------------------
extern "C" void kernel_launch(void* const* d_in, const int* in_sizes, int n_in,
                              void* d_out, int out_size, void* d_ws, size_t ws_size,
                              hipStream_t stream) {
  const float* x   = (const float*)d_in[0];
  const float* wq  = (const float*)d_in[1];
  const float* bq  = (const float*)d_in[2];
  const float* wk  = (const float*)d_in[3];
  const float* bk  = (const float*)d_in[4];
  const float* wv  = (const float*)d_in[5];
  const float* bv  = (const float*)d_in[6];
  const float* wo  = (const float*)d_in[7];
  const float* bo  = (const float*)d_in[8];
  const float* w1  = (const float*)d_in[9];
  const float* b1  = (const float*)d_in[10];
  const float* w2  = (const float*)d_in[11];
  const float* b2  = (const float*)d_in[12];
  const float* g1  = (const float*)d_in[13];
  const float* be1 = (const float*)d_in[14];
  const float* g2  = (const float*)d_in[15];
  const float* be2 = (const float*)d_in[16];
  float* out = (float*)d_out;

  char* ws = (char*)d_ws;
  const size_t MB = 1u << 20;
  bf16* qb    = (bf16*)(ws + 0);         // 16 MiB  [B,H,S,DH]
  bf16* kb    = (bf16*)(ws + 16 * MB);   // 16 MiB  [B,H,S,DH]
  bf16* vvb   = (bf16*)(ws + 32 * MB);   // 16 MiB  [B,H,DH,S]  (transposed!)
  bf16* xb    = (bf16*)(ws + 48 * MB);   // 16 MiB  [B*S, D]
  bf16* hb    = (bf16*)(ws + 0);         // 64 MiB, reuses q/k/v/xb after attn
  bf16* ctx   = (bf16*)(ws + 64 * MB);   // 16 MiB  [B*S, H*DH]
  float* y    = (float*)(ws + 80 * MB);  // 32 MiB  f32 (attn-out, then ffn-out)
  float* x1f  = (float*)(ws + 112 * MB); // 32 MiB  f32 post-LN1
  bf16* x1b   = (bf16*)(ws + 144 * MB);  // 16 MiB  bf16 post-LN1
  bf16* btqkv = (bf16*)(ws + 160 * MB);  // 6 MiB   [3072][1024]
  bf16* wot   = (bf16*)(ws + 166 * MB);  // 2 MiB   [1024][1024]
  bf16* w1t   = (bf16*)(ws + 168 * MB);  // 8 MiB   [4096][1024]
  bf16* w2t   = (bf16*)(ws + 176 * MB);  // 8 MiB   [1024][4096]

  // --- weight/activation conversion ---
  f32_to_bf16_vec<<<8192, 256, 0, stream>>>(x, xb, Bb * Ss * Dd / 4);
  transpose_f32_bf16<<<dim3(2, 32, 16), 256, 0, stream>>>(wq, btqkv + 0 * 1048576,
                                                          Dd, DHh, 65536, 65536);
  transpose_f32_bf16<<<dim3(2, 32, 16), 256, 0, stream>>>(wk, btqkv + 1 * 1048576,
                                                          Dd, DHh, 65536, 65536);
  transpose_f32_bf16<<<dim3(2, 32, 16), 256, 0, stream>>>(wv, btqkv + 2 * 1048576,
                                                          Dd, DHh, 65536, 65536);
  transpose_f32_bf16<<<dim3(32, 32, 1), 256, 0, stream>>>(wo, wot, Hh * DHh, Dd, 0, 0);
  transpose_f32_bf16<<<dim3(128, 32, 1), 256, 0, stream>>>(w1, w1t, Dd, FFf, 0, 0);
  transpose_f32_bf16<<<dim3(32, 128, 1), 256, 0, stream>>>(w2, w2t, FFf, Dd, 0, 0);

  // --- QKV projection (V written transposed per head) ---
  gemm_bt<EPI_QKV><<<dim3(64, 24), 256, 0, stream>>>(
      xb, btqkv, Bb * Ss, 3 * Hh * DHh, Dd, bq, bk, bv, qb, kb, vvb);

  // --- attention ---
  attn_kernel<<<2048, 256, 0, stream>>>(qb, kb, vvb, ctx);

  // --- output projection ---
  gemm_bt<EPI_WO><<<dim3(64, 8), 256, 0, stream>>>(
      ctx, wot, Bb * Ss, Dd, Hh * DHh, bo, nullptr, nullptr, y, nullptr, nullptr);

  // --- residual + LN1 ---
  ln_fused<<<Bb * Ss, 256, 0, stream>>>(x, y, g1, be1, x1f, x1b);

  // --- FFN ---
  gemm_bt<EPI_FFN1><<<dim3(64, 32), 256, 0, stream>>>(
      x1b, w1t, Bb * Ss, FFf, Dd, b1, nullptr, nullptr, hb, nullptr, nullptr);
  gemm_bt<EPI_FFN2><<<dim3(64, 8), 256, 0, stream>>>(
      hb, w2t, Bb * Ss, Dd, FFf, b2, nullptr, nullptr, y, nullptr, nullptr);

  // --- residual + LN2 -> out ---
  ln_fused<<<Bb * Ss, 256, 0, stream>>>(x1f, y, g2, be2, out, nullptr);
}